// Round 9
// baseline (1011.067 us; speedup 1.0000x reference)
//
#include <hip/hip_runtime.h>
#include <stdint.h>

// ---------- common types / helpers ----------
typedef __attribute__((ext_vector_type(8))) short bf8;   // 8 x bf16 (4 VGPRs)
typedef __attribute__((ext_vector_type(4))) float f4;    // MFMA accumulator

__device__ __forceinline__ float bf2f(uint16_t u) {
  union { unsigned i; float f; } v; v.i = ((unsigned)u) << 16; return v.f;
}
__device__ __forceinline__ uint16_t f2bf(float f) {
  union { float f; unsigned i; } v; v.f = f;
  unsigned r = v.i + 0x7fffu + ((v.i >> 16) & 1u);   // RTNE
  return (uint16_t)(r >> 16);
}
__device__ __forceinline__ bf8 cvt8(float4 a, float4 b) {
  bf8 r;
  r[0]=(short)f2bf(a.x); r[1]=(short)f2bf(a.y); r[2]=(short)f2bf(a.z); r[3]=(short)f2bf(a.w);
  r[4]=(short)f2bf(b.x); r[5]=(short)f2bf(b.y); r[6]=(short)f2bf(b.z); r[7]=(short)f2bf(b.w);
  return r;
}
// packed f32x2 -> bf16x2 (RNE); dst.lo = cvt(a), dst.hi = cvt(b)  [T12 recipe]
__device__ __forceinline__ uint32_t cvtpk(float a, float b) {
  uint32_t r;
  asm("v_cvt_pk_bf16_f32 %0, %1, %2" : "=v"(r) : "v"(a), "v"(b));
  return r;
}

// async global->LDS, 16B per lane, wave-uniform LDS base + lane*16
__device__ __forceinline__ void gload_lds16(const void* g, void* l) {
  __builtin_amdgcn_global_load_lds(
      (const __attribute__((address_space(1))) uint32_t*)(uintptr_t)g,
      (__attribute__((address_space(3))) uint32_t*)(uint32_t)(uintptr_t)l,
      16, 0, 0);
}

// ---------- f32 -> bf16 bulk convert ----------
__global__ __launch_bounds__(256)
void eagle3_cvt(const float* __restrict__ src, uint16_t* __restrict__ dst, int n8)
{
  int i = blockIdx.x * 256 + threadIdx.x;
  const int stride = gridDim.x * 256;
  for (; i < n8; i += stride) {
    const float4 a = ((const float4*)src)[i * 2];
    const float4 b = ((const float4*)src)[i * 2 + 1];
    ((bf8*)dst)[i] = cvt8(a, b);
  }
}

// ---------- GEMM v2 (128x128, m97 structure) : C = A * B^T, bf16 ----------
template<bool OF32>
__global__ __launch_bounds__(256)
void eagle3_gemm2(const uint16_t* __restrict__ Ap, const uint16_t* __restrict__ Bp,
                  void* __restrict__ Cp, int K, int lda, int ldb, int ldc)
{
  __shared__ __align__(16) uint16_t As[128 * 32];
  __shared__ __align__(16) uint16_t Bs[128 * 32];

  const int nwg = gridDim.x * gridDim.y;
  const int bid = blockIdx.y * gridDim.x + blockIdx.x;
  const int qq = nwg >> 3;
  const int sw = (bid & 7) * qq + (bid >> 3);
  const int bx = sw % gridDim.x, by = sw / gridDim.x;
  const int m0 = by * 128, n0 = bx * 128;

  const int tid = threadIdx.x, lane = tid & 63, w = tid >> 6;
  const int tl = lane & 15, g = lane >> 4;
  const int wr = (w >> 1) * 64, wc = (w & 1) * 64;

  f4 acc[4][4] = {};

  for (int k0 = 0; k0 < K; k0 += 32) {
    __syncthreads();
    #pragma unroll
    for (int i = 0; i < 2; ++i) {
      const int o = (w * 2 + i) * 1024 + lane * 16;
      const int r = o >> 6;
      const int u = (((o >> 4) & 3) ^ ((r >> 1) & 3)) * 8;
      gload_lds16(Ap + (size_t)(m0 + r) * lda + k0 + u, &As[(w * 2 + i) * 512]);
    }
    #pragma unroll
    for (int i = 0; i < 2; ++i) {
      const int o = (w * 2 + i) * 1024 + lane * 16;
      const int r = o >> 6;
      const int u = (((o >> 4) & 3) ^ ((r >> 1) & 3)) * 8;
      gload_lds16(Bp + (size_t)(n0 + r) * ldb + k0 + u, &Bs[(w * 2 + i) * 512]);
    }
    __syncthreads();

    bf8 af[4], bf_[4];
    #pragma unroll
    for (int i = 0; i < 4; ++i) {
      const int ar = wr + i * 16 + tl;
      const int br = wc + i * 16 + tl;
      af[i]  = *(const bf8*)&As[ar * 32 + ((g ^ ((ar >> 1) & 3)) * 8)];
      bf_[i] = *(const bf8*)&Bs[br * 32 + ((g ^ ((br >> 1) & 3)) * 8)];
    }
    #pragma unroll
    for (int mi = 0; mi < 4; ++mi)
      #pragma unroll
      for (int ni = 0; ni < 4; ++ni)
        acc[mi][ni] = __builtin_amdgcn_mfma_f32_16x16x32_bf16(af[mi], bf_[ni], acc[mi][ni], 0, 0, 0);
  }

  #pragma unroll
  for (int mi = 0; mi < 4; ++mi) {
    #pragma unroll
    for (int r = 0; r < 4; ++r) {
      const int row = m0 + wr + mi * 16 + g * 4 + r;
      #pragma unroll
      for (int ni = 0; ni < 4; ++ni) {
        const int col = n0 + wc + ni * 16 + tl;
        const float v = acc[mi][ni][r];
        if constexpr (OF32) ((float*)Cp)[(size_t)row * ldc + col] = v;
        else                ((uint16_t*)Cp)[(size_t)row * ldc + col] = f2bf(v);
      }
    }
  }
}

// ---------- GEMM v3b (256x256, BK=64 double-buffer) : C = A * B^T, bf16 ----
// 512 threads (8 waves = 2Mx4N, each 128x64 out, acc 8x4). LDS 2 slots x
// (A 32KB + B 32KB) = 128KB. flash4-proven sync pattern: STAGE(t+1) -> slot^1,
// vmcnt(8) (exactly the previous tile's 8 loads/thread), s_barrier, compute
// 64 MFMAs + 24 ds_reads, s_barrier. Row-XOR chunk swizzle (c ^= r&7) on the
// pre-swizzled global source + same XOR on the fragment read: 128B rows ->
// read pairs (tl, tl+8) per 16B window = free 2-way.
// Block mapping: 4m x 8n per XCD (grid 16x16) -> 12 concurrent panels/XCD.
template<bool OF32>
__global__ __launch_bounds__(512, 2)
void eagle3_gemm3(const uint16_t* __restrict__ Ap, const uint16_t* __restrict__ Bp,
                  void* __restrict__ Cp, int K, int lda, int ldb, int ldc)
{
  __shared__ __align__(16) uint16_t As[2][256 * 64];
  __shared__ __align__(16) uint16_t Bs[2][256 * 64];

  int bx, by;
  const int bid = blockIdx.y * gridDim.x + blockIdx.x;
  if (gridDim.x == 16 && gridDim.y == 16) {
    const int x = bid & 7, j = bid >> 3;     // XCD x, local block j
    by = (x >> 1) * 4 + (j >> 3);
    bx = (x & 1) * 8 + (j & 7);
  } else {
    const int nwg = gridDim.x * gridDim.y;
    const int qq = nwg >> 3;
    const int sw = (bid & 7) * qq + (bid >> 3);
    bx = sw % gridDim.x; by = sw / gridDim.x;
  }
  const int m0 = by * 256, n0 = bx * 256;

  const int tid = threadIdx.x, lane = tid & 63;
  const int tl = lane & 15, g = lane >> 4;
  const int w = tid >> 6;                 // 0..7
  const int wm = w >> 2, wn = w & 3;      // 2 x 4
  const int wr = wm * 128, wc = wn * 64;

  f4 acc[8][4] = {};
  const int NT = K >> 6;

  const int r_  = tid >> 3;                       // staging row 0..63 (+i*64)
  const int cs_ = ((tid & 7) ^ (r_ & 7)) * 8;     // pre-swizzled col (elems)

  // 8 gload_lds16 per thread per tile (4 A + 4 B), chunk j = i*512+tid:
  // row = i*64 + (tid>>3), 16B slot = tid&7; LDS linear, source swizzled.
  #define STAGE3(tt, slot)                                                      \
    {                                                                           \
      const int kk = (tt) << 6;                                                 \
      _Pragma("unroll")                                                         \
      for (int i = 0; i < 4; ++i) {                                             \
        gload_lds16(Ap + (size_t)(m0 + i * 64 + r_) * lda + kk + cs_,           \
                    &As[slot][(i * 512 + tid) * 8]);                            \
        gload_lds16(Bp + (size_t)(n0 + i * 64 + r_) * ldb + kk + cs_,           \
                    &Bs[slot][(i * 512 + tid) * 8]);                            \
      }                                                                         \
    }

  STAGE3(0, 0);

  for (int t = 0; t < NT; ++t) {
    const int cur = t & 1;
    if (t + 1 < NT) {
      STAGE3(t + 1, cur ^ 1);
      asm volatile("s_waitcnt vmcnt(8)" ::: "memory");   // tile t landed
    } else {
      asm volatile("s_waitcnt vmcnt(0)" ::: "memory");
    }
    __builtin_amdgcn_sched_barrier(0);
    __builtin_amdgcn_s_barrier();          // whole tile visible to all waves

    #pragma unroll
    for (int kh = 0; kh < 2; ++kh) {
      const int rcc = (((kh * 4) + g) ^ (tl & 7)) * 8;   // read-side XOR
      bf8 af[8], bfr[4];
      #pragma unroll
      for (int i = 0; i < 8; ++i)
        af[i] = *(const bf8*)&As[cur][(wr + i * 16 + tl) * 64 + rcc];
      #pragma unroll
      for (int i = 0; i < 4; ++i)
        bfr[i] = *(const bf8*)&Bs[cur][(wc + i * 16 + tl) * 64 + rcc];
      __builtin_amdgcn_s_setprio(1);
      #pragma unroll
      for (int mi = 0; mi < 8; ++mi)
        #pragma unroll
        for (int ni = 0; ni < 4; ++ni)
          acc[mi][ni] = __builtin_amdgcn_mfma_f32_16x16x32_bf16(af[mi], bfr[ni], acc[mi][ni], 0, 0, 0);
      __builtin_amdgcn_s_setprio(0);
    }

    __builtin_amdgcn_s_barrier();          // reads of slot cur done before
  }                                        // iteration t+1 restages into it
  #undef STAGE3

  // epilogue: C/D layout col=lane&15, row=(lane>>4)*4+reg
  #pragma unroll
  for (int mi = 0; mi < 8; ++mi) {
    #pragma unroll
    for (int r = 0; r < 4; ++r) {
      const int row = m0 + wr + mi * 16 + g * 4 + r;
      #pragma unroll
      for (int ni = 0; ni < 4; ++ni) {
        const int col = n0 + wc + ni * 16 + tl;
        const float v = acc[mi][ni][r];
        if constexpr (OF32) ((float*)Cp)[(size_t)row * ldc + col] = v;
        else                ((uint16_t*)Cp)[(size_t)row * ldc + col] = f2bf(v);
      }
    }
  }
}

// ---------- RoPE (in-place on bf16, pairs (d, d+64)) ----------
__global__ __launch_bounds__(256)
void eagle3_rope(uint16_t* __restrict__ x, const float* __restrict__ cs,
                 const float* __restrict__ sn, int nh, int rowlen, int total)
{
  int id = blockIdx.x * 256 + threadIdx.x;
  if (id >= total) return;
  int d = id & 63;
  int t = id >> 6;
  int head = t & (nh - 1);
  int row = t / nh;
  int s = row & 2047;
  size_t base = (size_t)row * rowlen + head * 128;
  float c = cs[s * 128 + d], si = sn[s * 128 + d];
  float x1 = bf2f(x[base + d]), x2 = bf2f(x[base + d + 64]);
  x[base + d]      = f2bf(x1 * c - x2 * si);
  x[base + d + 64] = f2bf(x2 * c + x1 * si);
}

// ---------- V transpose: [b,t,h,d] -> [b,h,d,t] ----------
__global__ __launch_bounds__(256)
void eagle3_vtrans(const uint16_t* __restrict__ V, uint16_t* __restrict__ Vt)
{
  __shared__ uint16_t T[64 * 136];
  const int tid = threadIdx.x;
  const int t0 = blockIdx.x * 64;
  const int bh = blockIdx.y;
  const int b = bh >> 3, h = bh & 7;
  {
    const int r = tid >> 2, c0 = (tid & 3) * 32;
    const uint16_t* src = V + (size_t)(b * 2048 + t0 + r) * 1024 + h * 128 + c0;
    #pragma unroll
    for (int j = 0; j < 4; ++j)
      *(bf8*)&T[r * 136 + c0 + j * 8] = *(const bf8*)(src + j * 8);
  }
  __syncthreads();
  {
    const int d = tid >> 1, tc = (tid & 1) * 32;
    uint16_t* dst = Vt + ((size_t)bh * 128 + d) * 2048 + t0 + tc;
    #pragma unroll
    for (int cc = 0; cc < 4; ++cc) {
      bf8 v;
      #pragma unroll
      for (int j = 0; j < 8; ++j) v[j] = T[(tc + cc * 8 + j) * 136 + d];
      *(bf8*)&dst[cc * 8] = v;
    }
  }
}

// ---------- causal GQA flash attention v5 (unchanged from round 8) ----------
__global__ __launch_bounds__(256, 2)
void eagle3_flash5(const uint16_t* __restrict__ Q, const uint16_t* __restrict__ Kt,
                   const uint16_t* __restrict__ Vt, uint16_t* __restrict__ O)
{
  __shared__ __align__(16) uint16_t Ks[2][64 * 128];
  __shared__ __align__(16) uint16_t Vs[2][128 * 64];
  __shared__ __align__(16) uint16_t Pl[4][16 * 72];

  const int tid = threadIdx.x, lane = tid & 63, w = tid >> 6;
  const int tl = lane & 15, g = lane >> 4;

  const int bid = (int)blockIdx.x + ((int)blockIdx.y << 5) + ((int)blockIdx.z << 10);
  const int xcd = bid & 7, idx = bid >> 3;
  const int grp = xcd * 2 + (idx >> 7);
  const int j   = idx & 127;
  const int b = grp >> 3, hkv = grp & 7;
  const int hq = hkv * 4 + (j & 3);
  const int qt = 31 - (j >> 2);
  const int qrow0 = qt * 64 + w * 16;
  const int ntb = qt + 1;

  bf8 qf[4];
  {
    const uint16_t* qp = Q + ((size_t)(b * 2048 + qrow0 + tl)) * 4096 + hq * 128 + g * 8;
    #pragma unroll
    for (int kb = 0; kb < 4; ++kb) qf[kb] = *(const bf8*)(qp + kb * 32);
  }

  const uint16_t* Kbase = Kt + (size_t)b * 2048 * 1024 + hkv * 128;
  const uint16_t* Vtb   = Vt + ((size_t)(b * 8 + hkv) * 128) * 2048;

  // ones B-fragment: B[k][0] = 1.0 -> MFMA computes row-sums in col 0
  bf8 onesf = {};
  if (tl == 0) {
    #pragma unroll
    for (int q8 = 0; q8 < 8; ++q8) onesf[q8] = (short)0x3F80;
  }

  f4 acc[8] = {};
  f4 accl = {};                               // softmax denominators (col 0)
  float rm[4] = {-3e38f, -3e38f, -3e38f, -3e38f};
  const float KS = 0.1275174f;                // log2(e)/sqrt(128)

  #define STAGE_TILE(buf, t0s)                                                   \
    {                                                                            \
      _Pragma("unroll")                                                          \
      for (int i = 0; i < 4; ++i) {                                              \
        const int f = i * 256 + tid;                                             \
        const int r = f >> 4, c = f & 15;                                        \
        gload_lds16(Kbase + (size_t)((t0s) + r) * 1024 + ((c ^ (r & 7)) * 8),    \
                    &Ks[buf][(i * 256 + w * 64) * 8]);                           \
      }                                                                          \
      _Pragma("unroll")                                                          \
      for (int i = 0; i < 4; ++i) {                                              \
        const int f = i * 256 + tid;                                             \
        const int d = f >> 3, c = f & 7;                                         \
        gload_lds16(Vtb + (size_t)d * 2048 + (t0s) + ((c ^ (d & 7)) * 8),        \
                    &Vs[buf][(i * 256 + w * 64) * 8]);                           \
      }                                                                          \
    }

  STAGE_TILE(0, 0);

  for (int tb = 0; tb < ntb; ++tb) {
    const int cur = tb & 1;
    const int t0 = tb * 64;

    if (tb + 1 < ntb) {
      STAGE_TILE(cur ^ 1, t0 + 64);
      asm volatile("s_waitcnt vmcnt(8)" ::: "memory");
    } else {
      asm volatile("s_waitcnt vmcnt(0)" ::: "memory");
    }
    __builtin_amdgcn_sched_barrier(0);
    __builtin_amdgcn_s_barrier();

    // -- QK^T (raw scores) --
    f4 s[4] = {};
    __builtin_amdgcn_s_setprio(1);
    #pragma unroll
    for (int cf = 0; cf < 4; ++cf) {
      #pragma unroll
      for (int kb = 0; kb < 4; ++kb) {
        const bf8 kf = *(const bf8*)&Ks[cur][(cf * 16 + tl) * 128 +
                                            (((kb * 4 + g) ^ (tl & 7)) * 8)];
        s[cf] = __builtin_amdgcn_mfma_f32_16x16x32_bf16(qf[kb], kf, s[cf], 0, 0, 0);
      }
    }
    __builtin_amdgcn_s_setprio(0);

    // -- online softmax (raw domain; mask only on the edge tile) --
    const bool edge = (tb == ntb - 1);
    float p[4][4];
    #pragma unroll
    for (int r = 0; r < 4; ++r) {
      float v[4];
      #pragma unroll
      for (int cf = 0; cf < 4; ++cf) v[cf] = s[cf][r];
      if (edge) {
        const int qg = qrow0 + g * 4 + r;
        #pragma unroll
        for (int cf = 0; cf < 4; ++cf)
          if (t0 + cf * 16 + tl > qg) v[cf] = -3e38f;
      }
      float mx = fmaxf(fmaxf(v[0], v[1]), fmaxf(v[2], v[3]));
      mx = fmaxf(mx, __shfl_xor(mx, 1));
      mx = fmaxf(mx, __shfl_xor(mx, 2));
      mx = fmaxf(mx, __shfl_xor(mx, 4));
      mx = fmaxf(mx, __shfl_xor(mx, 8));
      if (mx > rm[r]) {
        const float corr = exp2f((rm[r] - mx) * KS);
        #pragma unroll
        for (int df = 0; df < 8; ++df) acc[df][r] *= corr;
        accl[r] *= corr;
        rm[r] = mx;
      }
      #pragma unroll
      for (int cf = 0; cf < 4; ++cf) p[r][cf] = exp2f((v[cf] - rm[r]) * KS);
    }

    // -- P -> LDS via cvt_pk, re-read as A-fragments --
    #pragma unroll
    for (int r = 0; r < 4; ++r) {
      const uint32_t pk0 = cvtpk(p[r][0], p[r][1]);
      const uint32_t pk1 = cvtpk(p[r][2], p[r][3]);
      uint16_t* Pw = &Pl[w][(g * 4 + r) * 72 + tl];
      Pw[0]  = (uint16_t)pk0;
      Pw[16] = (uint16_t)(pk0 >> 16);
      Pw[32] = (uint16_t)pk1;
      Pw[48] = (uint16_t)(pk1 >> 16);
    }
    const bf8 pf0 = *(const bf8*)&Pl[w][tl * 72 + g * 8];
    const bf8 pf1 = *(const bf8*)&Pl[w][tl * 72 + 32 + g * 8];

    // -- PV + denominator MFMAs --
    __builtin_amdgcn_s_setprio(1);
    accl = __builtin_amdgcn_mfma_f32_16x16x32_bf16(pf0, onesf, accl, 0, 0, 0);
    accl = __builtin_amdgcn_mfma_f32_16x16x32_bf16(pf1, onesf, accl, 0, 0, 0);
    #pragma unroll
    for (int df = 0; df < 8; ++df) {
      const int vrow = (df * 16 + tl) * 64;
      const bf8 v0 = *(const bf8*)&Vs[cur][vrow + ((g ^ (tl & 7)) * 8)];
      const bf8 v1 = *(const bf8*)&Vs[cur][vrow + (((4 + g) ^ (tl & 7)) * 8)];
      acc[df] = __builtin_amdgcn_mfma_f32_16x16x32_bf16(pf0, v0, acc[df], 0, 0, 0);
      acc[df] = __builtin_amdgcn_mfma_f32_16x16x32_bf16(pf1, v1, acc[df], 0, 0, 0);
    }
    __builtin_amdgcn_s_setprio(0);

    __builtin_amdgcn_s_barrier();
  }
  #undef STAGE_TILE

  // -- normalize (l broadcast from col-0 lane of each 16-lane group) + store --
  #pragma unroll
  for (int r = 0; r < 4; ++r) {
    const float l = __shfl(accl[r], lane & 48);
    const float inv = 1.0f / l;
    const size_t ob = ((size_t)(b * 2048 + qrow0 + g * 4 + r)) * 4096 + hq * 128 + tl;
    #pragma unroll
    for (int df = 0; df < 8; ++df)
      O[ob + df * 16] = f2bf(acc[df][r] * inv);
  }
}

// ---------- launch ----------
extern "C" void kernel_launch(void* const* d_in, const int* in_sizes, int n_in,
                              void* d_out, int out_size, void* d_ws, size_t ws_size,
                              hipStream_t stream) {
  const float* hs   = (const float*)d_in[0];
  const float* cosT = (const float*)d_in[2];
  const float* sinT = (const float*)d_in[3];
  const float* Wq   = (const float*)d_in[4];
  const float* Wk   = (const float*)d_in[5];
  const float* Wv   = (const float*)d_in[6];
  const float* Wo   = (const float*)d_in[7];

  char* ws = (char*)d_ws;
  uint16_t* qb    = (uint16_t*)(ws);
  uint16_t* kbuf  = (uint16_t*)(ws + 33554432);
  uint16_t* vbuf  = (uint16_t*)(ws + 41943040);
  uint16_t* whalf = (uint16_t*)(ws + 50331648);
  uint16_t* vt    = (uint16_t*)(ws + 75497472);
  uint16_t* ctx   = (uint16_t*)(ws + 41943040);
  uint16_t* hsb   = (uint16_t*)d_out;
  uint16_t* wobf  = qb;

  const dim3 blk(256);
  const bool fullq = (ws_size >= (size_t)117440512);   // 112 MiB

  // 1) hs f32 -> bf16 (once)
  eagle3_cvt<<<dim3(2048), blk, 0, stream>>>(hs, hsb, 4194304);

  // 2) Q projection
  if (fullq) {
    eagle3_cvt<<<dim3(2048), blk, 0, stream>>>(Wq, whalf, 4194304);
    eagle3_gemm3<false><<<dim3(16, 16), dim3(512), 0, stream>>>(
        hsb, whalf, (void*)qb, 8192, 8192, 8192, 4096);
  } else {
    eagle3_cvt<<<dim3(2048), blk, 0, stream>>>(Wq, whalf, 2097152);
    eagle3_gemm2<false><<<dim3(16, 32), blk, 0, stream>>>(
        hsb, whalf, (void*)qb, 8192, 8192, 8192, 4096);
    eagle3_cvt<<<dim3(2048), blk, 0, stream>>>(Wq + 16777216, whalf, 2097152);
    eagle3_gemm2<false><<<dim3(16, 32), blk, 0, stream>>>(
        hsb, whalf, (void*)(qb + 2048), 8192, 8192, 8192, 4096);
  }

  // 3) K and V projections
  eagle3_cvt<<<dim3(2048), blk, 0, stream>>>(Wk, whalf, 1048576);
  eagle3_gemm2<false><<<dim3(8, 32), blk, 0, stream>>>(
      hsb, whalf, (void*)kbuf, 8192, 8192, 8192, 1024);
  eagle3_cvt<<<dim3(2048), blk, 0, stream>>>(Wv, whalf, 1048576);
  eagle3_gemm2<false><<<dim3(8, 32), blk, 0, stream>>>(
      hsb, whalf, (void*)vbuf, 8192, 8192, 8192, 1024);

  // 4) RoPE + V transpose
  eagle3_rope<<<dim3(32768), blk, 0, stream>>>(qb, cosT, sinT, 32, 4096, 8388608);
  eagle3_rope<<<dim3(8192), blk, 0, stream>>>(kbuf, cosT, sinT, 8, 1024, 2097152);
  eagle3_vtrans<<<dim3(32, 16), blk, 0, stream>>>(vbuf, vt);

  // 5) causal GQA flash attention -> ctx
  eagle3_flash5<<<dim3(32, 32, 2), blk, 0, stream>>>(qb, kbuf, vt, ctx);

  // 6) output projection: out = ctx * Wo^T (f32 out over dead hsb)
  eagle3_cvt<<<dim3(2048), blk, 0, stream>>>(Wo, wobf, 2097152);
  eagle3_gemm3<true><<<dim3(16, 16), dim3(512), 0, stream>>>(
      ctx, wobf, d_out, 4096, 4096, 4096, 4096);
}

// Round 10
// 998.758 us; speedup vs baseline: 1.0123x; 1.0123x over previous
//
#include <hip/hip_runtime.h>
#include <stdint.h>

// ---------- common types / helpers ----------
typedef __attribute__((ext_vector_type(8))) short bf8;   // 8 x bf16 (4 VGPRs)
typedef __attribute__((ext_vector_type(4))) float f4;    // MFMA accumulator

__device__ __forceinline__ float bf2f(uint16_t u) {
  union { unsigned i; float f; } v; v.i = ((unsigned)u) << 16; return v.f;
}
__device__ __forceinline__ uint16_t f2bf(float f) {
  union { float f; unsigned i; } v; v.f = f;
  unsigned r = v.i + 0x7fffu + ((v.i >> 16) & 1u);   // RTNE
  return (uint16_t)(r >> 16);
}
__device__ __forceinline__ bf8 cvt8(float4 a, float4 b) {
  bf8 r;
  r[0]=(short)f2bf(a.x); r[1]=(short)f2bf(a.y); r[2]=(short)f2bf(a.z); r[3]=(short)f2bf(a.w);
  r[4]=(short)f2bf(b.x); r[5]=(short)f2bf(b.y); r[6]=(short)f2bf(b.z); r[7]=(short)f2bf(b.w);
  return r;
}
// packed f32x2 -> bf16x2 (RNE); dst.lo = cvt(a), dst.hi = cvt(b)  [T12 recipe]
__device__ __forceinline__ uint32_t cvtpk(float a, float b) {
  uint32_t r;
  asm("v_cvt_pk_bf16_f32 %0, %1, %2" : "=v"(r) : "v"(a), "v"(b));
  return r;
}

// async global->LDS, 16B per lane, wave-uniform LDS base + lane*16
__device__ __forceinline__ void gload_lds16(const void* g, void* l) {
  __builtin_amdgcn_global_load_lds(
      (const __attribute__((address_space(1))) uint32_t*)(uintptr_t)g,
      (__attribute__((address_space(3))) uint32_t*)(uint32_t)(uintptr_t)l,
      16, 0, 0);
}

// ---------- f32 -> bf16 bulk convert ----------
__global__ __launch_bounds__(256)
void eagle3_cvt(const float* __restrict__ src, uint16_t* __restrict__ dst, int n8)
{
  int i = blockIdx.x * 256 + threadIdx.x;
  const int stride = gridDim.x * 256;
  for (; i < n8; i += stride) {
    const float4 a = ((const float4*)src)[i * 2];
    const float4 b = ((const float4*)src)[i * 2 + 1];
    ((bf8*)dst)[i] = cvt8(a, b);
  }
}

// ---------- GEMM v2 (128x128, m97 structure) : C = A * B^T, bf16 ----------
template<bool OF32>
__global__ __launch_bounds__(256)
void eagle3_gemm2(const uint16_t* __restrict__ Ap, const uint16_t* __restrict__ Bp,
                  void* __restrict__ Cp, int K, int lda, int ldb, int ldc)
{
  __shared__ __align__(16) uint16_t As[128 * 32];
  __shared__ __align__(16) uint16_t Bs[128 * 32];

  const int nwg = gridDim.x * gridDim.y;
  const int bid = blockIdx.y * gridDim.x + blockIdx.x;
  const int qq = nwg >> 3;
  const int sw = (bid & 7) * qq + (bid >> 3);
  const int bx = sw % gridDim.x, by = sw / gridDim.x;
  const int m0 = by * 128, n0 = bx * 128;

  const int tid = threadIdx.x, lane = tid & 63, w = tid >> 6;
  const int tl = lane & 15, g = lane >> 4;
  const int wr = (w >> 1) * 64, wc = (w & 1) * 64;

  f4 acc[4][4] = {};

  for (int k0 = 0; k0 < K; k0 += 32) {
    __syncthreads();
    #pragma unroll
    for (int i = 0; i < 2; ++i) {
      const int o = (w * 2 + i) * 1024 + lane * 16;
      const int r = o >> 6;
      const int u = (((o >> 4) & 3) ^ ((r >> 1) & 3)) * 8;
      gload_lds16(Ap + (size_t)(m0 + r) * lda + k0 + u, &As[(w * 2 + i) * 512]);
    }
    #pragma unroll
    for (int i = 0; i < 2; ++i) {
      const int o = (w * 2 + i) * 1024 + lane * 16;
      const int r = o >> 6;
      const int u = (((o >> 4) & 3) ^ ((r >> 1) & 3)) * 8;
      gload_lds16(Bp + (size_t)(n0 + r) * ldb + k0 + u, &Bs[(w * 2 + i) * 512]);
    }
    __syncthreads();

    bf8 af[4], bf_[4];
    #pragma unroll
    for (int i = 0; i < 4; ++i) {
      const int ar = wr + i * 16 + tl;
      const int br = wc + i * 16 + tl;
      af[i]  = *(const bf8*)&As[ar * 32 + ((g ^ ((ar >> 1) & 3)) * 8)];
      bf_[i] = *(const bf8*)&Bs[br * 32 + ((g ^ ((br >> 1) & 3)) * 8)];
    }
    #pragma unroll
    for (int mi = 0; mi < 4; ++mi)
      #pragma unroll
      for (int ni = 0; ni < 4; ++ni)
        acc[mi][ni] = __builtin_amdgcn_mfma_f32_16x16x32_bf16(af[mi], bf_[ni], acc[mi][ni], 0, 0, 0);
  }

  #pragma unroll
  for (int mi = 0; mi < 4; ++mi) {
    #pragma unroll
    for (int r = 0; r < 4; ++r) {
      const int row = m0 + wr + mi * 16 + g * 4 + r;
      #pragma unroll
      for (int ni = 0; ni < 4; ++ni) {
        const int col = n0 + wc + ni * 16 + tl;
        const float v = acc[mi][ni][r];
        if constexpr (OF32) ((float*)Cp)[(size_t)row * ldc + col] = v;
        else                ((uint16_t*)Cp)[(size_t)row * ldc + col] = f2bf(v);
      }
    }
  }
}

// ---------- GEMM v3 (256x256, BK=32, 4-deep ring) : C = A * B^T, bf16 ----
// Round-8-proven inner structure (258us, 0 bank conflicts): 4 ring slots,
// 2-3 tiles in DMA flight, vmcnt(8/4/0) ladder, one barrier per K-step.
// Round-9-proven block mapping (FETCH 500->213MB): 4m x 8n panels per XCD,
// all 32 co-resident blocks of an XCD share a ~1-2MB rolling L2 window.
// Both-sides XOR chunk swizzle (c ^= (row>>1)&3), pre-swizzled global source.
template<bool OF32>
__global__ __launch_bounds__(512, 2)
void eagle3_gemm3(const uint16_t* __restrict__ Ap, const uint16_t* __restrict__ Bp,
                  void* __restrict__ Cp, int K, int lda, int ldb, int ldc)
{
  __shared__ __align__(16) uint16_t As[4][256 * 32];
  __shared__ __align__(16) uint16_t Bs[4][256 * 32];

  int bx, by;
  const int bid = blockIdx.y * gridDim.x + blockIdx.x;
  if (gridDim.x == 16 && gridDim.y == 16) {
    const int x = bid & 7, j = bid >> 3;     // XCD x, local block j (0..31)
    by = (x >> 1) * 4 + (j >> 3);            // 4 m-panels per XCD
    bx = (x & 1) * 8 + (j & 7);              // 8 n-panels per XCD
  } else {
    const int nwg = gridDim.x * gridDim.y;
    const int qq = nwg >> 3;
    const int sw = (bid & 7) * qq + (bid >> 3);
    bx = sw % gridDim.x; by = sw / gridDim.x;
  }
  const int m0 = by * 256, n0 = bx * 256;

  const int tid = threadIdx.x, lane = tid & 63;
  const int tl = lane & 15, g = lane >> 4;
  const int w = tid >> 6;                 // 0..7
  const int wm = w >> 2, wn = w & 3;      // 2 x 4
  const int wr = wm * 128, wc = wn * 64;

  f4 acc[8][4] = {};
  const int NT = K >> 5;

  // thread t stages chunks j = t, t+512 of each 256x32 tile: row j>>2,
  // slot j&3 (LDS linear); global source chunk pre-swizzled by (row>>1)&3.
  #define STAGE3(tt)                                                            \
    {                                                                           \
      const int kk = (tt) << 5;                                                 \
      const int bsel_ = (tt) & 3;                                               \
      const int r_ = tid >> 2;                                                  \
      const int cs_ = ((tid & 3) ^ ((r_ >> 1) & 3)) * 8;                        \
      gload_lds16(Ap + (size_t)(m0 + r_) * lda + kk + cs_,                      \
                  &As[bsel_][tid * 8]);                                         \
      gload_lds16(Ap + (size_t)(m0 + 128 + r_) * lda + kk + cs_,                \
                  &As[bsel_][(tid + 512) * 8]);                                 \
      gload_lds16(Bp + (size_t)(n0 + r_) * ldb + kk + cs_,                      \
                  &Bs[bsel_][tid * 8]);                                         \
      gload_lds16(Bp + (size_t)(n0 + 128 + r_) * ldb + kk + cs_,                \
                  &Bs[bsel_][(tid + 512) * 8]);                                 \
    }

  STAGE3(0);
  if (NT > 1) STAGE3(1);
  if (NT > 2) STAGE3(2);

  // fragment-read swizzle: (ar>>1)&3 == (tl>>1)&3 for all our row offsets
  const int rc = (g ^ ((tl >> 1) & 3)) * 8;

  for (int t = 0; t < NT; ++t) {
    if (t + 2 < NT)      asm volatile("s_waitcnt vmcnt(8)" ::: "memory");
    else if (t + 1 < NT) asm volatile("s_waitcnt vmcnt(4)" ::: "memory");
    else                 asm volatile("s_waitcnt vmcnt(0)" ::: "memory");
    __builtin_amdgcn_sched_barrier(0);
    __builtin_amdgcn_s_barrier();          // tile t visible; slot t-1 reads done
    __builtin_amdgcn_sched_barrier(0);

    if (t + 3 < NT) STAGE3(t + 3);         // -> slot (t+3)%4 == (t-1)%4, safe

    const int bsel = t & 3;
    bf8 af[8], bfr[4];
    #pragma unroll
    for (int i = 0; i < 8; ++i)
      af[i] = *(const bf8*)&As[bsel][(wr + i * 16 + tl) * 32 + rc];
    #pragma unroll
    for (int i = 0; i < 4; ++i)
      bfr[i] = *(const bf8*)&Bs[bsel][(wc + i * 16 + tl) * 32 + rc];

    __builtin_amdgcn_s_setprio(1);
    #pragma unroll
    for (int mi = 0; mi < 8; ++mi)
      #pragma unroll
      for (int ni = 0; ni < 4; ++ni)
        acc[mi][ni] = __builtin_amdgcn_mfma_f32_16x16x32_bf16(af[mi], bfr[ni], acc[mi][ni], 0, 0, 0);
    __builtin_amdgcn_s_setprio(0);
  }
  #undef STAGE3

  // epilogue: C/D layout col=lane&15, row=(lane>>4)*4+reg
  #pragma unroll
  for (int mi = 0; mi < 8; ++mi) {
    #pragma unroll
    for (int r = 0; r < 4; ++r) {
      const int row = m0 + wr + mi * 16 + g * 4 + r;
      #pragma unroll
      for (int ni = 0; ni < 4; ++ni) {
        const int col = n0 + wc + ni * 16 + tl;
        const float v = acc[mi][ni][r];
        if constexpr (OF32) ((float*)Cp)[(size_t)row * ldc + col] = v;
        else                ((uint16_t*)Cp)[(size_t)row * ldc + col] = f2bf(v);
      }
    }
  }
}

// ---------- RoPE (in-place on bf16, pairs (d, d+64)) ----------
__global__ __launch_bounds__(256)
void eagle3_rope(uint16_t* __restrict__ x, const float* __restrict__ cs,
                 const float* __restrict__ sn, int nh, int rowlen, int total)
{
  int id = blockIdx.x * 256 + threadIdx.x;
  if (id >= total) return;
  int d = id & 63;
  int t = id >> 6;
  int head = t & (nh - 1);
  int row = t / nh;
  int s = row & 2047;
  size_t base = (size_t)row * rowlen + head * 128;
  float c = cs[s * 128 + d], si = sn[s * 128 + d];
  float x1 = bf2f(x[base + d]), x2 = bf2f(x[base + d + 64]);
  x[base + d]      = f2bf(x1 * c - x2 * si);
  x[base + d + 64] = f2bf(x2 * c + x1 * si);
}

// ---------- V transpose: [b,t,h,d] -> [b,h,d,t] ----------
__global__ __launch_bounds__(256)
void eagle3_vtrans(const uint16_t* __restrict__ V, uint16_t* __restrict__ Vt)
{
  __shared__ uint16_t T[64 * 136];
  const int tid = threadIdx.x;
  const int t0 = blockIdx.x * 64;
  const int bh = blockIdx.y;
  const int b = bh >> 3, h = bh & 7;
  {
    const int r = tid >> 2, c0 = (tid & 3) * 32;
    const uint16_t* src = V + (size_t)(b * 2048 + t0 + r) * 1024 + h * 128 + c0;
    #pragma unroll
    for (int j = 0; j < 4; ++j)
      *(bf8*)&T[r * 136 + c0 + j * 8] = *(const bf8*)(src + j * 8);
  }
  __syncthreads();
  {
    const int d = tid >> 1, tc = (tid & 1) * 32;
    uint16_t* dst = Vt + ((size_t)bh * 128 + d) * 2048 + t0 + tc;
    #pragma unroll
    for (int cc = 0; cc < 4; ++cc) {
      bf8 v;
      #pragma unroll
      for (int j = 0; j < 8; ++j) v[j] = T[(tc + cc * 8 + j) * 136 + d];
      *(bf8*)&dst[cc * 8] = v;
    }
  }
}

// ---------- causal GQA flash attention v5 (unchanged) ----------
__global__ __launch_bounds__(256, 2)
void eagle3_flash5(const uint16_t* __restrict__ Q, const uint16_t* __restrict__ Kt,
                   const uint16_t* __restrict__ Vt, uint16_t* __restrict__ O)
{
  __shared__ __align__(16) uint16_t Ks[2][64 * 128];
  __shared__ __align__(16) uint16_t Vs[2][128 * 64];
  __shared__ __align__(16) uint16_t Pl[4][16 * 72];

  const int tid = threadIdx.x, lane = tid & 63, w = tid >> 6;
  const int tl = lane & 15, g = lane >> 4;

  const int bid = (int)blockIdx.x + ((int)blockIdx.y << 5) + ((int)blockIdx.z << 10);
  const int xcd = bid & 7, idx = bid >> 3;
  const int grp = xcd * 2 + (idx >> 7);
  const int j   = idx & 127;
  const int b = grp >> 3, hkv = grp & 7;
  const int hq = hkv * 4 + (j & 3);
  const int qt = 31 - (j >> 2);
  const int qrow0 = qt * 64 + w * 16;
  const int ntb = qt + 1;

  bf8 qf[4];
  {
    const uint16_t* qp = Q + ((size_t)(b * 2048 + qrow0 + tl)) * 4096 + hq * 128 + g * 8;
    #pragma unroll
    for (int kb = 0; kb < 4; ++kb) qf[kb] = *(const bf8*)(qp + kb * 32);
  }

  const uint16_t* Kbase = Kt + (size_t)b * 2048 * 1024 + hkv * 128;
  const uint16_t* Vtb   = Vt + ((size_t)(b * 8 + hkv) * 128) * 2048;

  // ones B-fragment: B[k][0] = 1.0 -> MFMA computes row-sums in col 0
  bf8 onesf = {};
  if (tl == 0) {
    #pragma unroll
    for (int q8 = 0; q8 < 8; ++q8) onesf[q8] = (short)0x3F80;
  }

  f4 acc[8] = {};
  f4 accl = {};                               // softmax denominators (col 0)
  float rm[4] = {-3e38f, -3e38f, -3e38f, -3e38f};
  const float KS = 0.1275174f;                // log2(e)/sqrt(128)

  #define STAGE_TILE(buf, t0s)                                                   \
    {                                                                            \
      _Pragma("unroll")                                                          \
      for (int i = 0; i < 4; ++i) {                                              \
        const int f = i * 256 + tid;                                             \
        const int r = f >> 4, c = f & 15;                                        \
        gload_lds16(Kbase + (size_t)((t0s) + r) * 1024 + ((c ^ (r & 7)) * 8),    \
                    &Ks[buf][(i * 256 + w * 64) * 8]);                           \
      }                                                                          \
      _Pragma("unroll")                                                          \
      for (int i = 0; i < 4; ++i) {                                              \
        const int f = i * 256 + tid;                                             \
        const int d = f >> 3, c = f & 7;                                         \
        gload_lds16(Vtb + (size_t)d * 2048 + (t0s) + ((c ^ (d & 7)) * 8),        \
                    &Vs[buf][(i * 256 + w * 64) * 8]);                           \
      }                                                                          \
    }

  STAGE_TILE(0, 0);

  for (int tb = 0; tb < ntb; ++tb) {
    const int cur = tb & 1;
    const int t0 = tb * 64;

    if (tb + 1 < ntb) {
      STAGE_TILE(cur ^ 1, t0 + 64);
      asm volatile("s_waitcnt vmcnt(8)" ::: "memory");
    } else {
      asm volatile("s_waitcnt vmcnt(0)" ::: "memory");
    }
    __builtin_amdgcn_sched_barrier(0);
    __builtin_amdgcn_s_barrier();

    // -- QK^T (raw scores) --
    f4 s[4] = {};
    __builtin_amdgcn_s_setprio(1);
    #pragma unroll
    for (int cf = 0; cf < 4; ++cf) {
      #pragma unroll
      for (int kb = 0; kb < 4; ++kb) {
        const bf8 kf = *(const bf8*)&Ks[cur][(cf * 16 + tl) * 128 +
                                            (((kb * 4 + g) ^ (tl & 7)) * 8)];
        s[cf] = __builtin_amdgcn_mfma_f32_16x16x32_bf16(qf[kb], kf, s[cf], 0, 0, 0);
      }
    }
    __builtin_amdgcn_s_setprio(0);

    // -- online softmax (raw domain; mask only on the edge tile) --
    const bool edge = (tb == ntb - 1);
    float p[4][4];
    #pragma unroll
    for (int r = 0; r < 4; ++r) {
      float v[4];
      #pragma unroll
      for (int cf = 0; cf < 4; ++cf) v[cf] = s[cf][r];
      if (edge) {
        const int qg = qrow0 + g * 4 + r;
        #pragma unroll
        for (int cf = 0; cf < 4; ++cf)
          if (t0 + cf * 16 + tl > qg) v[cf] = -3e38f;
      }
      float mx = fmaxf(fmaxf(v[0], v[1]), fmaxf(v[2], v[3]));
      mx = fmaxf(mx, __shfl_xor(mx, 1));
      mx = fmaxf(mx, __shfl_xor(mx, 2));
      mx = fmaxf(mx, __shfl_xor(mx, 4));
      mx = fmaxf(mx, __shfl_xor(mx, 8));
      if (mx > rm[r]) {
        const float corr = exp2f((rm[r] - mx) * KS);
        #pragma unroll
        for (int df = 0; df < 8; ++df) acc[df][r] *= corr;
        accl[r] *= corr;
        rm[r] = mx;
      }
      #pragma unroll
      for (int cf = 0; cf < 4; ++cf) p[r][cf] = exp2f((v[cf] - rm[r]) * KS);
    }

    // -- P -> LDS via cvt_pk, re-read as A-fragments --
    #pragma unroll
    for (int r = 0; r < 4; ++r) {
      const uint32_t pk0 = cvtpk(p[r][0], p[r][1]);
      const uint32_t pk1 = cvtpk(p[r][2], p[r][3]);
      uint16_t* Pw = &Pl[w][(g * 4 + r) * 72 + tl];
      Pw[0]  = (uint16_t)pk0;
      Pw[16] = (uint16_t)(pk0 >> 16);
      Pw[32] = (uint16_t)pk1;
      Pw[48] = (uint16_t)(pk1 >> 16);
    }
    const bf8 pf0 = *(const bf8*)&Pl[w][tl * 72 + g * 8];
    const bf8 pf1 = *(const bf8*)&Pl[w][tl * 72 + 32 + g * 8];

    // -- PV + denominator MFMAs --
    __builtin_amdgcn_s_setprio(1);
    accl = __builtin_amdgcn_mfma_f32_16x16x32_bf16(pf0, onesf, accl, 0, 0, 0);
    accl = __builtin_amdgcn_mfma_f32_16x16x32_bf16(pf1, onesf, accl, 0, 0, 0);
    #pragma unroll
    for (int df = 0; df < 8; ++df) {
      const int vrow = (df * 16 + tl) * 64;
      const bf8 v0 = *(const bf8*)&Vs[cur][vrow + ((g ^ (tl & 7)) * 8)];
      const bf8 v1 = *(const bf8*)&Vs[cur][vrow + (((4 + g) ^ (tl & 7)) * 8)];
      acc[df] = __builtin_amdgcn_mfma_f32_16x16x32_bf16(pf0, v0, acc[df], 0, 0, 0);
      acc[df] = __builtin_amdgcn_mfma_f32_16x16x32_bf16(pf1, v1, acc[df], 0, 0, 0);
    }
    __builtin_amdgcn_s_setprio(0);

    __builtin_amdgcn_s_barrier();
  }
  #undef STAGE_TILE

  // -- normalize (l broadcast from col-0 lane of each 16-lane group) + store --
  #pragma unroll
  for (int r = 0; r < 4; ++r) {
    const float l = __shfl(accl[r], lane & 48);
    const float inv = 1.0f / l;
    const size_t ob = ((size_t)(b * 2048 + qrow0 + g * 4 + r)) * 4096 + hq * 128 + tl;
    #pragma unroll
    for (int df = 0; df < 8; ++df)
      O[ob + df * 16] = f2bf(acc[df][r] * inv);
  }
}

// ---------- launch ----------
extern "C" void kernel_launch(void* const* d_in, const int* in_sizes, int n_in,
                              void* d_out, int out_size, void* d_ws, size_t ws_size,
                              hipStream_t stream) {
  const float* hs   = (const float*)d_in[0];
  const float* cosT = (const float*)d_in[2];
  const float* sinT = (const float*)d_in[3];
  const float* Wq   = (const float*)d_in[4];
  const float* Wk   = (const float*)d_in[5];
  const float* Wv   = (const float*)d_in[6];
  const float* Wo   = (const float*)d_in[7];

  char* ws = (char*)d_ws;
  uint16_t* qb    = (uint16_t*)(ws);
  uint16_t* kbuf  = (uint16_t*)(ws + 33554432);
  uint16_t* vbuf  = (uint16_t*)(ws + 41943040);
  uint16_t* whalf = (uint16_t*)(ws + 50331648);
  uint16_t* vt    = (uint16_t*)(ws + 75497472);
  uint16_t* ctx   = (uint16_t*)(ws + 41943040);
  uint16_t* hsb   = (uint16_t*)d_out;
  uint16_t* wobf  = qb;

  const dim3 blk(256);
  const bool fullq = (ws_size >= (size_t)117440512);   // 112 MiB

  // 1) hs f32 -> bf16 (once)
  eagle3_cvt<<<dim3(2048), blk, 0, stream>>>(hs, hsb, 4194304);

  // 2) Q projection
  if (fullq) {
    eagle3_cvt<<<dim3(2048), blk, 0, stream>>>(Wq, whalf, 4194304);
    eagle3_gemm3<false><<<dim3(16, 16), dim3(512), 0, stream>>>(
        hsb, whalf, (void*)qb, 8192, 8192, 8192, 4096);
  } else {
    eagle3_cvt<<<dim3(2048), blk, 0, stream>>>(Wq, whalf, 2097152);
    eagle3_gemm2<false><<<dim3(16, 32), blk, 0, stream>>>(
        hsb, whalf, (void*)qb, 8192, 8192, 8192, 4096);
    eagle3_cvt<<<dim3(2048), blk, 0, stream>>>(Wq + 16777216, whalf, 2097152);
    eagle3_gemm2<false><<<dim3(16, 32), blk, 0, stream>>>(
        hsb, whalf, (void*)(qb + 2048), 8192, 8192, 8192, 4096);
  }

  // 3) K and V projections
  eagle3_cvt<<<dim3(2048), blk, 0, stream>>>(Wk, whalf, 1048576);
  eagle3_gemm2<false><<<dim3(8, 32), blk, 0, stream>>>(
      hsb, whalf, (void*)kbuf, 8192, 8192, 8192, 1024);
  eagle3_cvt<<<dim3(2048), blk, 0, stream>>>(Wv, whalf, 1048576);
  eagle3_gemm2<false><<<dim3(8, 32), blk, 0, stream>>>(
      hsb, whalf, (void*)vbuf, 8192, 8192, 8192, 1024);

  // 4) RoPE + V transpose
  eagle3_rope<<<dim3(32768), blk, 0, stream>>>(qb, cosT, sinT, 32, 4096, 8388608);
  eagle3_rope<<<dim3(8192), blk, 0, stream>>>(kbuf, cosT, sinT, 8, 1024, 2097152);
  eagle3_vtrans<<<dim3(32, 16), blk, 0, stream>>>(vbuf, vt);

  // 5) causal GQA flash attention -> ctx
  eagle3_flash5<<<dim3(32, 32, 2), blk, 0, stream>>>(qb, kbuf, vt, ctx);

  // 6) output projection: out = ctx * Wo^T (f32 out over dead hsb)
  eagle3_cvt<<<dim3(2048), blk, 0, stream>>>(Wo, wobf, 2097152);
  eagle3_gemm3<true><<<dim3(16, 16), dim3(512), 0, stream>>>(
      ctx, wobf, d_out, 4096, 4096, 4096, 4096);
}

// Round 11
// 938.463 us; speedup vs baseline: 1.0774x; 1.0642x over previous
//
#include <hip/hip_runtime.h>
#include <stdint.h>

// ---------- common types / helpers ----------
typedef __attribute__((ext_vector_type(8))) short bf8;   // 8 x bf16 (4 VGPRs)
typedef __attribute__((ext_vector_type(4))) float f4;    // MFMA accumulator

__device__ __forceinline__ float bf2f(uint16_t u) {
  union { unsigned i; float f; } v; v.i = ((unsigned)u) << 16; return v.f;
}
__device__ __forceinline__ uint16_t f2bf(float f) {
  union { float f; unsigned i; } v; v.f = f;
  unsigned r = v.i + 0x7fffu + ((v.i >> 16) & 1u);   // RTNE
  return (uint16_t)(r >> 16);
}
__device__ __forceinline__ bf8 cvt8(float4 a, float4 b) {
  bf8 r;
  r[0]=(short)f2bf(a.x); r[1]=(short)f2bf(a.y); r[2]=(short)f2bf(a.z); r[3]=(short)f2bf(a.w);
  r[4]=(short)f2bf(b.x); r[5]=(short)f2bf(b.y); r[6]=(short)f2bf(b.z); r[7]=(short)f2bf(b.w);
  return r;
}
// packed f32x2 -> bf16x2 (RNE); dst.lo = cvt(a), dst.hi = cvt(b)  [T12 recipe]
__device__ __forceinline__ uint32_t cvtpk(float a, float b) {
  uint32_t r;
  asm("v_cvt_pk_bf16_f32 %0, %1, %2" : "=v"(r) : "v"(a), "v"(b));
  return r;
}

// async global->LDS, 16B per lane, wave-uniform LDS base + lane*16
__device__ __forceinline__ void gload_lds16(const void* g, void* l) {
  __builtin_amdgcn_global_load_lds(
      (const __attribute__((address_space(1))) uint32_t*)(uintptr_t)g,
      (__attribute__((address_space(3))) uint32_t*)(uint32_t)(uintptr_t)l,
      16, 0, 0);
}

// ---------- f32 -> bf16 bulk convert ----------
__global__ __launch_bounds__(256)
void eagle3_cvt(const float* __restrict__ src, uint16_t* __restrict__ dst, int n8)
{
  int i = blockIdx.x * 256 + threadIdx.x;
  const int stride = gridDim.x * 256;
  for (; i < n8; i += stride) {
    const float4 a = ((const float4*)src)[i * 2];
    const float4 b = ((const float4*)src)[i * 2 + 1];
    ((bf8*)dst)[i] = cvt8(a, b);
  }
}

// ---------- GEMM v2 (128x128, m97 structure) : C = A * B^T, bf16 ----------
template<bool OF32>
__global__ __launch_bounds__(256)
void eagle3_gemm2(const uint16_t* __restrict__ Ap, const uint16_t* __restrict__ Bp,
                  void* __restrict__ Cp, int K, int lda, int ldb, int ldc)
{
  __shared__ __align__(16) uint16_t As[128 * 32];
  __shared__ __align__(16) uint16_t Bs[128 * 32];

  const int nwg = gridDim.x * gridDim.y;
  const int bid = blockIdx.y * gridDim.x + blockIdx.x;
  const int qq = nwg >> 3;
  const int sw = (bid & 7) * qq + (bid >> 3);
  const int bx = sw % gridDim.x, by = sw / gridDim.x;
  const int m0 = by * 128, n0 = bx * 128;

  const int tid = threadIdx.x, lane = tid & 63, w = tid >> 6;
  const int tl = lane & 15, g = lane >> 4;
  const int wr = (w >> 1) * 64, wc = (w & 1) * 64;

  f4 acc[4][4] = {};

  for (int k0 = 0; k0 < K; k0 += 32) {
    __syncthreads();
    #pragma unroll
    for (int i = 0; i < 2; ++i) {
      const int o = (w * 2 + i) * 1024 + lane * 16;
      const int r = o >> 6;
      const int u = (((o >> 4) & 3) ^ ((r >> 1) & 3)) * 8;
      gload_lds16(Ap + (size_t)(m0 + r) * lda + k0 + u, &As[(w * 2 + i) * 512]);
    }
    #pragma unroll
    for (int i = 0; i < 2; ++i) {
      const int o = (w * 2 + i) * 1024 + lane * 16;
      const int r = o >> 6;
      const int u = (((o >> 4) & 3) ^ ((r >> 1) & 3)) * 8;
      gload_lds16(Bp + (size_t)(n0 + r) * ldb + k0 + u, &Bs[(w * 2 + i) * 512]);
    }
    __syncthreads();

    bf8 af[4], bf_[4];
    #pragma unroll
    for (int i = 0; i < 4; ++i) {
      const int ar = wr + i * 16 + tl;
      const int br = wc + i * 16 + tl;
      af[i]  = *(const bf8*)&As[ar * 32 + ((g ^ ((ar >> 1) & 3)) * 8)];
      bf_[i] = *(const bf8*)&Bs[br * 32 + ((g ^ ((br >> 1) & 3)) * 8)];
    }
    #pragma unroll
    for (int mi = 0; mi < 4; ++mi)
      #pragma unroll
      for (int ni = 0; ni < 4; ++ni)
        acc[mi][ni] = __builtin_amdgcn_mfma_f32_16x16x32_bf16(af[mi], bf_[ni], acc[mi][ni], 0, 0, 0);
  }

  #pragma unroll
  for (int mi = 0; mi < 4; ++mi) {
    #pragma unroll
    for (int r = 0; r < 4; ++r) {
      const int row = m0 + wr + mi * 16 + g * 4 + r;
      #pragma unroll
      for (int ni = 0; ni < 4; ++ni) {
        const int col = n0 + wc + ni * 16 + tl;
        const float v = acc[mi][ni][r];
        if constexpr (OF32) ((float*)Cp)[(size_t)row * ldc + col] = v;
        else                ((uint16_t*)Cp)[(size_t)row * ldc + col] = f2bf(v);
      }
    }
  }
}

// ---------- GEMM v3 (256x256, BK=32, 4-deep ring) : C = A * B^T, bf16 ----
// Round-8 inner structure (0 conflicts) + round-9 XCD panel mapping (213MB).
template<bool OF32>
__global__ __launch_bounds__(512, 2)
void eagle3_gemm3(const uint16_t* __restrict__ Ap, const uint16_t* __restrict__ Bp,
                  void* __restrict__ Cp, int K, int lda, int ldb, int ldc)
{
  __shared__ __align__(16) uint16_t As[4][256 * 32];
  __shared__ __align__(16) uint16_t Bs[4][256 * 32];

  int bx, by;
  const int bid = blockIdx.y * gridDim.x + blockIdx.x;
  if (gridDim.x == 16 && gridDim.y == 16) {
    const int x = bid & 7, j = bid >> 3;     // XCD x, local block j (0..31)
    by = (x >> 1) * 4 + (j >> 3);            // 4 m-panels per XCD
    bx = (x & 1) * 8 + (j & 7);              // 8 n-panels per XCD
  } else {
    const int nwg = gridDim.x * gridDim.y;
    const int qq = nwg >> 3;
    const int sw = (bid & 7) * qq + (bid >> 3);
    bx = sw % gridDim.x; by = sw / gridDim.x;
  }
  const int m0 = by * 256, n0 = bx * 256;

  const int tid = threadIdx.x, lane = tid & 63;
  const int tl = lane & 15, g = lane >> 4;
  const int w = tid >> 6;                 // 0..7
  const int wm = w >> 2, wn = w & 3;      // 2 x 4
  const int wr = wm * 128, wc = wn * 64;

  f4 acc[8][4] = {};
  const int NT = K >> 5;

  #define STAGE3(tt)                                                            \
    {                                                                           \
      const int kk = (tt) << 5;                                                 \
      const int bsel_ = (tt) & 3;                                               \
      const int r_ = tid >> 2;                                                  \
      const int cs_ = ((tid & 3) ^ ((r_ >> 1) & 3)) * 8;                        \
      gload_lds16(Ap + (size_t)(m0 + r_) * lda + kk + cs_,                      \
                  &As[bsel_][tid * 8]);                                         \
      gload_lds16(Ap + (size_t)(m0 + 128 + r_) * lda + kk + cs_,                \
                  &As[bsel_][(tid + 512) * 8]);                                 \
      gload_lds16(Bp + (size_t)(n0 + r_) * ldb + kk + cs_,                      \
                  &Bs[bsel_][tid * 8]);                                         \
      gload_lds16(Bp + (size_t)(n0 + 128 + r_) * ldb + kk + cs_,                \
                  &Bs[bsel_][(tid + 512) * 8]);                                 \
    }

  STAGE3(0);
  if (NT > 1) STAGE3(1);
  if (NT > 2) STAGE3(2);

  const int rc = (g ^ ((tl >> 1) & 3)) * 8;

  for (int t = 0; t < NT; ++t) {
    if (t + 2 < NT)      asm volatile("s_waitcnt vmcnt(8)" ::: "memory");
    else if (t + 1 < NT) asm volatile("s_waitcnt vmcnt(4)" ::: "memory");
    else                 asm volatile("s_waitcnt vmcnt(0)" ::: "memory");
    __builtin_amdgcn_sched_barrier(0);
    __builtin_amdgcn_s_barrier();
    __builtin_amdgcn_sched_barrier(0);

    if (t + 3 < NT) STAGE3(t + 3);

    const int bsel = t & 3;
    bf8 af[8], bfr[4];
    #pragma unroll
    for (int i = 0; i < 8; ++i)
      af[i] = *(const bf8*)&As[bsel][(wr + i * 16 + tl) * 32 + rc];
    #pragma unroll
    for (int i = 0; i < 4; ++i)
      bfr[i] = *(const bf8*)&Bs[bsel][(wc + i * 16 + tl) * 32 + rc];

    __builtin_amdgcn_s_setprio(1);
    #pragma unroll
    for (int mi = 0; mi < 8; ++mi)
      #pragma unroll
      for (int ni = 0; ni < 4; ++ni)
        acc[mi][ni] = __builtin_amdgcn_mfma_f32_16x16x32_bf16(af[mi], bfr[ni], acc[mi][ni], 0, 0, 0);
    __builtin_amdgcn_s_setprio(0);
  }
  #undef STAGE3

  #pragma unroll
  for (int mi = 0; mi < 8; ++mi) {
    #pragma unroll
    for (int r = 0; r < 4; ++r) {
      const int row = m0 + wr + mi * 16 + g * 4 + r;
      #pragma unroll
      for (int ni = 0; ni < 4; ++ni) {
        const int col = n0 + wc + ni * 16 + tl;
        const float v = acc[mi][ni][r];
        if constexpr (OF32) ((float*)Cp)[(size_t)row * ldc + col] = v;
        else                ((uint16_t*)Cp)[(size_t)row * ldc + col] = f2bf(v);
      }
    }
  }
}

// ---------- RoPE (in-place on bf16, pairs (d, d+64)) ----------
__global__ __launch_bounds__(256)
void eagle3_rope(uint16_t* __restrict__ x, const float* __restrict__ cs,
                 const float* __restrict__ sn, int nh, int rowlen, int total)
{
  int id = blockIdx.x * 256 + threadIdx.x;
  if (id >= total) return;
  int d = id & 63;
  int t = id >> 6;
  int head = t & (nh - 1);
  int row = t / nh;
  int s = row & 2047;
  size_t base = (size_t)row * rowlen + head * 128;
  float c = cs[s * 128 + d], si = sn[s * 128 + d];
  float x1 = bf2f(x[base + d]), x2 = bf2f(x[base + d + 64]);
  x[base + d]      = f2bf(x1 * c - x2 * si);
  x[base + d + 64] = f2bf(x2 * c + x1 * si);
}

// ---------- V transpose: [b,t,h,d] -> [b,h,d,t] ----------
__global__ __launch_bounds__(256)
void eagle3_vtrans(const uint16_t* __restrict__ V, uint16_t* __restrict__ Vt)
{
  __shared__ uint16_t T[64 * 136];
  const int tid = threadIdx.x;
  const int t0 = blockIdx.x * 64;
  const int bh = blockIdx.y;
  const int b = bh >> 3, h = bh & 7;
  {
    const int r = tid >> 2, c0 = (tid & 3) * 32;
    const uint16_t* src = V + (size_t)(b * 2048 + t0 + r) * 1024 + h * 128 + c0;
    #pragma unroll
    for (int j = 0; j < 4; ++j)
      *(bf8*)&T[r * 136 + c0 + j * 8] = *(const bf8*)(src + j * 8);
  }
  __syncthreads();
  {
    const int d = tid >> 1, tc = (tid & 1) * 32;
    uint16_t* dst = Vt + ((size_t)bh * 128 + d) * 2048 + t0 + tc;
    #pragma unroll
    for (int cc = 0; cc < 4; ++cc) {
      bf8 v;
      #pragma unroll
      for (int j = 0; j < 8; ++j) v[j] = T[(tc + cc * 8 + j) * 136 + d];
      *(bf8*)&dst[cc * 8] = v;
    }
  }
}

// ---------- causal GQA flash attention v6 (QBLK=128, 8 waves, 2 blk/CU) ----
// 512 threads (8 waves x 16 q-rows), KVBLK=64 double-buffered. K/V staging
// amortized over 8 waves (4 gloads/thread -> vmcnt(4)). P-LDS uses the same
// XOR chunk swizzle as K/V ([16][64], chunk ^= row&7) so total LDS = exactly
// 80KB -> 2 blocks/CU = 4 waves/SIMD (2x the MFMA-duty ceiling of flash5).
__global__ __launch_bounds__(512, 4)
void eagle3_flash6(const uint16_t* __restrict__ Q, const uint16_t* __restrict__ Kt,
                   const uint16_t* __restrict__ Vt, uint16_t* __restrict__ O)
{
  __shared__ __align__(16) uint16_t Ks[2][64 * 128];   // 32 KB
  __shared__ __align__(16) uint16_t Vs[2][128 * 64];   // 32 KB
  __shared__ __align__(16) uint16_t Pl[8][16 * 64];    // 16 KB (per-wave, swz)

  const int tid = threadIdx.x, lane = tid & 63, w = tid >> 6;
  const int tl = lane & 15, g = lane >> 4;

  // grid (16,32,2) = 1024 blocks; 2 (b,hkv) groups per XCD, heavy-qt first,
  // 4 hq-blocks of a group at the same qt are bid-adjacent (share K/V tiles).
  const int bid = (int)blockIdx.x + ((int)blockIdx.y << 4) + ((int)blockIdx.z << 9);
  const int xcd = bid & 7, idx = bid >> 3;       // idx 0..127
  const int grp = xcd * 2 + (idx >> 6);          // b*8 + hkv
  const int j   = idx & 63;
  const int b = grp >> 3, hkv = grp & 7;
  const int hq = hkv * 4 + (j & 3);
  const int qt = 15 - (j >> 2);                  // 0..15, heavy first
  const int qrow0 = qt * 128 + w * 16;           // wave's 16 q-rows
  const int ntb = 2 * qt + 2;                    // 64-wide KV tiles

  bf8 qf[4];
  {
    const uint16_t* qp = Q + ((size_t)(b * 2048 + qrow0 + tl)) * 4096 + hq * 128 + g * 8;
    #pragma unroll
    for (int kb = 0; kb < 4; ++kb) qf[kb] = *(const bf8*)(qp + kb * 32);
  }

  const uint16_t* Kbase = Kt + (size_t)b * 2048 * 1024 + hkv * 128;   // [t][128]
  const uint16_t* Vtb   = Vt + ((size_t)(b * 8 + hkv) * 128) * 2048;  // [d][t]

  // ones B-fragment: B[k][0] = 1.0 -> MFMA computes row-sums in col 0
  bf8 onesf = {};
  if (tl == 0) {
    #pragma unroll
    for (int q8 = 0; q8 < 8; ++q8) onesf[q8] = (short)0x3F80;
  }

  f4 acc[8] = {};
  f4 accl = {};                               // softmax denominators (col 0)
  float rm[4] = {-3e38f, -3e38f, -3e38f, -3e38f};
  const float KS = 0.1275174f;                // log2(e)/sqrt(128)

  // 4 gloads/thread/tile (2 K + 2 V); wave-uniform LDS base + lane*16.
  #define STAGE_TILE(buf, t0s)                                                   \
    {                                                                            \
      _Pragma("unroll")                                                          \
      for (int i = 0; i < 2; ++i) {                                              \
        const int f = i * 512 + tid;                                             \
        const int r = f >> 4, c = f & 15;                                        \
        gload_lds16(Kbase + (size_t)((t0s) + r) * 1024 + ((c ^ (r & 7)) * 8),    \
                    &Ks[buf][(i * 512 + w * 64) * 8]);                           \
      }                                                                          \
      _Pragma("unroll")                                                          \
      for (int i = 0; i < 2; ++i) {                                              \
        const int f = i * 512 + tid;                                             \
        const int d = f >> 3, c = f & 7;                                         \
        gload_lds16(Vtb + (size_t)d * 2048 + (t0s) + ((c ^ (d & 7)) * 8),        \
                    &Vs[buf][(i * 512 + w * 64) * 8]);                           \
      }                                                                          \
    }

  STAGE_TILE(0, 0);

  for (int tb = 0; tb < ntb; ++tb) {
    const int cur = tb & 1;
    const int t0 = tb * 64;

    if (tb + 1 < ntb) {
      STAGE_TILE(cur ^ 1, t0 + 64);
      asm volatile("s_waitcnt vmcnt(4)" ::: "memory");   // tile tb landed
    } else {
      asm volatile("s_waitcnt vmcnt(0)" ::: "memory");
    }
    __builtin_amdgcn_sched_barrier(0);
    __builtin_amdgcn_s_barrier();

    // -- QK^T (raw scores): S(16x64) --
    f4 s[4] = {};
    __builtin_amdgcn_s_setprio(1);
    #pragma unroll
    for (int cf = 0; cf < 4; ++cf) {
      #pragma unroll
      for (int kb = 0; kb < 4; ++kb) {
        const bf8 kf = *(const bf8*)&Ks[cur][(cf * 16 + tl) * 128 +
                                            (((kb * 4 + g) ^ (tl & 7)) * 8)];
        s[cf] = __builtin_amdgcn_mfma_f32_16x16x32_bf16(qf[kb], kf, s[cf], 0, 0, 0);
      }
    }
    __builtin_amdgcn_s_setprio(0);

    // -- online softmax (raw domain; mask when tile can cross the diagonal) --
    const bool edge = (t0 + 63 > qrow0);        // wave-uniform
    float p[4][4];
    #pragma unroll
    for (int r = 0; r < 4; ++r) {
      float v[4];
      #pragma unroll
      for (int cf = 0; cf < 4; ++cf) v[cf] = s[cf][r];
      if (edge) {
        const int qg = qrow0 + g * 4 + r;
        #pragma unroll
        for (int cf = 0; cf < 4; ++cf)
          if (t0 + cf * 16 + tl > qg) v[cf] = -3e38f;
      }
      float mx = fmaxf(fmaxf(v[0], v[1]), fmaxf(v[2], v[3]));
      mx = fmaxf(mx, __shfl_xor(mx, 1));
      mx = fmaxf(mx, __shfl_xor(mx, 2));
      mx = fmaxf(mx, __shfl_xor(mx, 4));
      mx = fmaxf(mx, __shfl_xor(mx, 8));
      if (mx > rm[r]) {
        const float corr = exp2f((rm[r] - mx) * KS);
        #pragma unroll
        for (int df = 0; df < 8; ++df) acc[df][r] *= corr;
        accl[r] *= corr;
        rm[r] = mx;
      }
      #pragma unroll
      for (int cf = 0; cf < 4; ++cf) p[r][cf] = exp2f((v[cf] - rm[r]) * KS);
    }

    // -- P -> LDS (XOR-swizzled [16][64]): chunk(cf*2 + tl>>3) ^ (row&7) --
    #pragma unroll
    for (int r = 0; r < 4; ++r) {
      const uint32_t pk0 = cvtpk(p[r][0], p[r][1]);
      const uint32_t pk1 = cvtpk(p[r][2], p[r][3]);
      const int row = g * 4 + r;
      const int sw = row & 7;
      uint16_t* Pw = &Pl[w][row * 64 + (tl & 7)];
      Pw[(((tl >> 3) + 0) ^ sw) * 8] = (uint16_t)pk0;
      Pw[(((tl >> 3) + 2) ^ sw) * 8] = (uint16_t)(pk0 >> 16);
      Pw[(((tl >> 3) + 4) ^ sw) * 8] = (uint16_t)pk1;
      Pw[(((tl >> 3) + 6) ^ sw) * 8] = (uint16_t)(pk1 >> 16);
    }
    const bf8 pf0 = *(const bf8*)&Pl[w][tl * 64 + ((g ^ (tl & 7)) * 8)];
    const bf8 pf1 = *(const bf8*)&Pl[w][tl * 64 + (((4 + g) ^ (tl & 7)) * 8)];

    // -- PV + denominator MFMAs --
    __builtin_amdgcn_s_setprio(1);
    accl = __builtin_amdgcn_mfma_f32_16x16x32_bf16(pf0, onesf, accl, 0, 0, 0);
    accl = __builtin_amdgcn_mfma_f32_16x16x32_bf16(pf1, onesf, accl, 0, 0, 0);
    #pragma unroll
    for (int df = 0; df < 8; ++df) {
      const int vrow = (df * 16 + tl) * 64;
      const bf8 v0 = *(const bf8*)&Vs[cur][vrow + ((g ^ (tl & 7)) * 8)];
      const bf8 v1 = *(const bf8*)&Vs[cur][vrow + (((4 + g) ^ (tl & 7)) * 8)];
      acc[df] = __builtin_amdgcn_mfma_f32_16x16x32_bf16(pf0, v0, acc[df], 0, 0, 0);
      acc[df] = __builtin_amdgcn_mfma_f32_16x16x32_bf16(pf1, v1, acc[df], 0, 0, 0);
    }
    __builtin_amdgcn_s_setprio(0);

    __builtin_amdgcn_s_barrier();
  }
  #undef STAGE_TILE

  // -- normalize (l broadcast from col-0 lane of each 16-lane group) + store --
  #pragma unroll
  for (int r = 0; r < 4; ++r) {
    const float l = __shfl(accl[r], lane & 48);
    const float inv = 1.0f / l;
    const size_t ob = ((size_t)(b * 2048 + qrow0 + g * 4 + r)) * 4096 + hq * 128 + tl;
    #pragma unroll
    for (int df = 0; df < 8; ++df)
      O[ob + df * 16] = f2bf(acc[df][r] * inv);
  }
}

// ---------- launch ----------
extern "C" void kernel_launch(void* const* d_in, const int* in_sizes, int n_in,
                              void* d_out, int out_size, void* d_ws, size_t ws_size,
                              hipStream_t stream) {
  const float* hs   = (const float*)d_in[0];
  const float* cosT = (const float*)d_in[2];
  const float* sinT = (const float*)d_in[3];
  const float* Wq   = (const float*)d_in[4];
  const float* Wk   = (const float*)d_in[5];
  const float* Wv   = (const float*)d_in[6];
  const float* Wo   = (const float*)d_in[7];

  char* ws = (char*)d_ws;
  uint16_t* qb    = (uint16_t*)(ws);
  uint16_t* kbuf  = (uint16_t*)(ws + 33554432);
  uint16_t* vbuf  = (uint16_t*)(ws + 41943040);
  uint16_t* whalf = (uint16_t*)(ws + 50331648);
  uint16_t* vt    = (uint16_t*)(ws + 75497472);
  uint16_t* ctx   = (uint16_t*)(ws + 41943040);
  uint16_t* hsb   = (uint16_t*)d_out;
  uint16_t* wobf  = qb;

  const dim3 blk(256);
  const bool fullq = (ws_size >= (size_t)117440512);   // 112 MiB

  // 1) hs f32 -> bf16 (once)
  eagle3_cvt<<<dim3(2048), blk, 0, stream>>>(hs, hsb, 4194304);

  // 2) Q projection
  if (fullq) {
    eagle3_cvt<<<dim3(2048), blk, 0, stream>>>(Wq, whalf, 4194304);
    eagle3_gemm3<false><<<dim3(16, 16), dim3(512), 0, stream>>>(
        hsb, whalf, (void*)qb, 8192, 8192, 8192, 4096);
  } else {
    eagle3_cvt<<<dim3(2048), blk, 0, stream>>>(Wq, whalf, 2097152);
    eagle3_gemm2<false><<<dim3(16, 32), blk, 0, stream>>>(
        hsb, whalf, (void*)qb, 8192, 8192, 8192, 4096);
    eagle3_cvt<<<dim3(2048), blk, 0, stream>>>(Wq + 16777216, whalf, 2097152);
    eagle3_gemm2<false><<<dim3(16, 32), blk, 0, stream>>>(
        hsb, whalf, (void*)(qb + 2048), 8192, 8192, 8192, 4096);
  }

  // 3) K and V projections
  eagle3_cvt<<<dim3(2048), blk, 0, stream>>>(Wk, whalf, 1048576);
  eagle3_gemm2<false><<<dim3(8, 32), blk, 0, stream>>>(
      hsb, whalf, (void*)kbuf, 8192, 8192, 8192, 1024);
  eagle3_cvt<<<dim3(2048), blk, 0, stream>>>(Wv, whalf, 1048576);
  eagle3_gemm2<false><<<dim3(8, 32), blk, 0, stream>>>(
      hsb, whalf, (void*)vbuf, 8192, 8192, 8192, 1024);

  // 4) RoPE + V transpose
  eagle3_rope<<<dim3(32768), blk, 0, stream>>>(qb, cosT, sinT, 32, 4096, 8388608);
  eagle3_rope<<<dim3(8192), blk, 0, stream>>>(kbuf, cosT, sinT, 8, 1024, 2097152);
  eagle3_vtrans<<<dim3(32, 16), blk, 0, stream>>>(vbuf, vt);

  // 5) causal GQA flash attention -> ctx
  eagle3_flash6<<<dim3(16, 32, 2), dim3(512), 0, stream>>>(qb, kbuf, vt, ctx);

  // 6) output projection: out = ctx * Wo^T (f32 out over dead hsb)
  eagle3_cvt<<<dim3(2048), blk, 0, stream>>>(Wo, wobf, 2097152);
  eagle3_gemm3<true><<<dim3(16, 16), dim3(512), 0, stream>>>(
      ctx, wobf, d_out, 4096, 4096, 4096, 4096);
}

// Round 12
// 935.045 us; speedup vs baseline: 1.0813x; 1.0037x over previous
//
#include <hip/hip_runtime.h>
#include <stdint.h>

// ---------- common types / helpers ----------
typedef __attribute__((ext_vector_type(8))) short bf8;   // 8 x bf16 (4 VGPRs)
typedef __attribute__((ext_vector_type(4))) float f4;    // MFMA accumulator

__device__ __forceinline__ float bf2f(uint16_t u) {
  union { unsigned i; float f; } v; v.i = ((unsigned)u) << 16; return v.f;
}
__device__ __forceinline__ uint16_t f2bf(float f) {
  union { float f; unsigned i; } v; v.f = f;
  unsigned r = v.i + 0x7fffu + ((v.i >> 16) & 1u);   // RTNE
  return (uint16_t)(r >> 16);
}
__device__ __forceinline__ bf8 cvt8(float4 a, float4 b) {
  bf8 r;
  r[0]=(short)f2bf(a.x); r[1]=(short)f2bf(a.y); r[2]=(short)f2bf(a.z); r[3]=(short)f2bf(a.w);
  r[4]=(short)f2bf(b.x); r[5]=(short)f2bf(b.y); r[6]=(short)f2bf(b.z); r[7]=(short)f2bf(b.w);
  return r;
}
// packed f32x2 -> bf16x2 (RNE); dst.lo = cvt(a), dst.hi = cvt(b)  [T12 recipe]
__device__ __forceinline__ uint32_t cvtpk(float a, float b) {
  uint32_t r;
  asm("v_cvt_pk_bf16_f32 %0, %1, %2" : "=v"(r) : "v"(a), "v"(b));
  return r;
}

// async global->LDS, 16B per lane, wave-uniform LDS base + lane*16
__device__ __forceinline__ void gload_lds16(const void* g, void* l) {
  __builtin_amdgcn_global_load_lds(
      (const __attribute__((address_space(1))) uint32_t*)(uintptr_t)g,
      (__attribute__((address_space(3))) uint32_t*)(uint32_t)(uintptr_t)l,
      16, 0, 0);
}

// ---------- f32 -> bf16 bulk convert ----------
__global__ __launch_bounds__(256)
void eagle3_cvt(const float* __restrict__ src, uint16_t* __restrict__ dst, int n8)
{
  int i = blockIdx.x * 256 + threadIdx.x;
  const int stride = gridDim.x * 256;
  for (; i < n8; i += stride) {
    const float4 a = ((const float4*)src)[i * 2];
    const float4 b = ((const float4*)src)[i * 2 + 1];
    ((bf8*)dst)[i] = cvt8(a, b);
  }
}

// ---------- GEMM v2 (128x128, m97 structure) : C = A * B^T, bf16 ----------
template<bool OF32>
__global__ __launch_bounds__(256)
void eagle3_gemm2(const uint16_t* __restrict__ Ap, const uint16_t* __restrict__ Bp,
                  void* __restrict__ Cp, int K, int lda, int ldb, int ldc)
{
  __shared__ __align__(16) uint16_t As[128 * 32];
  __shared__ __align__(16) uint16_t Bs[128 * 32];

  const int nwg = gridDim.x * gridDim.y;
  const int bid = blockIdx.y * gridDim.x + blockIdx.x;
  const int qq = nwg >> 3;
  const int sw = (bid & 7) * qq + (bid >> 3);
  const int bx = sw % gridDim.x, by = sw / gridDim.x;
  const int m0 = by * 128, n0 = bx * 128;

  const int tid = threadIdx.x, lane = tid & 63, w = tid >> 6;
  const int tl = lane & 15, g = lane >> 4;
  const int wr = (w >> 1) * 64, wc = (w & 1) * 64;

  f4 acc[4][4] = {};

  for (int k0 = 0; k0 < K; k0 += 32) {
    __syncthreads();
    #pragma unroll
    for (int i = 0; i < 2; ++i) {
      const int o = (w * 2 + i) * 1024 + lane * 16;
      const int r = o >> 6;
      const int u = (((o >> 4) & 3) ^ ((r >> 1) & 3)) * 8;
      gload_lds16(Ap + (size_t)(m0 + r) * lda + k0 + u, &As[(w * 2 + i) * 512]);
    }
    #pragma unroll
    for (int i = 0; i < 2; ++i) {
      const int o = (w * 2 + i) * 1024 + lane * 16;
      const int r = o >> 6;
      const int u = (((o >> 4) & 3) ^ ((r >> 1) & 3)) * 8;
      gload_lds16(Bp + (size_t)(n0 + r) * ldb + k0 + u, &Bs[(w * 2 + i) * 512]);
    }
    __syncthreads();

    bf8 af[4], bf_[4];
    #pragma unroll
    for (int i = 0; i < 4; ++i) {
      const int ar = wr + i * 16 + tl;
      const int br = wc + i * 16 + tl;
      af[i]  = *(const bf8*)&As[ar * 32 + ((g ^ ((ar >> 1) & 3)) * 8)];
      bf_[i] = *(const bf8*)&Bs[br * 32 + ((g ^ ((br >> 1) & 3)) * 8)];
    }
    #pragma unroll
    for (int mi = 0; mi < 4; ++mi)
      #pragma unroll
      for (int ni = 0; ni < 4; ++ni)
        acc[mi][ni] = __builtin_amdgcn_mfma_f32_16x16x32_bf16(af[mi], bf_[ni], acc[mi][ni], 0, 0, 0);
  }

  #pragma unroll
  for (int mi = 0; mi < 4; ++mi) {
    #pragma unroll
    for (int r = 0; r < 4; ++r) {
      const int row = m0 + wr + mi * 16 + g * 4 + r;
      #pragma unroll
      for (int ni = 0; ni < 4; ++ni) {
        const int col = n0 + wc + ni * 16 + tl;
        const float v = acc[mi][ni][r];
        if constexpr (OF32) ((float*)Cp)[(size_t)row * ldc + col] = v;
        else                ((uint16_t*)Cp)[(size_t)row * ldc + col] = f2bf(v);
      }
    }
  }
}

// ---------- GEMM v3 (256x256, BK=32, 4-deep ring) : C = A * B^T, bf16 ----
// Round-8 inner structure (0 conflicts) + round-9 XCD panel mapping (213MB).
template<bool OF32>
__global__ __launch_bounds__(512, 2)
void eagle3_gemm3(const uint16_t* __restrict__ Ap, const uint16_t* __restrict__ Bp,
                  void* __restrict__ Cp, int K, int lda, int ldb, int ldc)
{
  __shared__ __align__(16) uint16_t As[4][256 * 32];
  __shared__ __align__(16) uint16_t Bs[4][256 * 32];

  int bx, by;
  const int bid = blockIdx.y * gridDim.x + blockIdx.x;
  if (gridDim.x == 16 && gridDim.y == 16) {
    const int x = bid & 7, j = bid >> 3;     // XCD x, local block j (0..31)
    by = (x >> 1) * 4 + (j >> 3);            // 4 m-panels per XCD
    bx = (x & 1) * 8 + (j & 7);              // 8 n-panels per XCD
  } else {
    const int nwg = gridDim.x * gridDim.y;
    const int qq = nwg >> 3;
    const int sw = (bid & 7) * qq + (bid >> 3);
    bx = sw % gridDim.x; by = sw / gridDim.x;
  }
  const int m0 = by * 256, n0 = bx * 256;

  const int tid = threadIdx.x, lane = tid & 63;
  const int tl = lane & 15, g = lane >> 4;
  const int w = tid >> 6;                 // 0..7
  const int wm = w >> 2, wn = w & 3;      // 2 x 4
  const int wr = wm * 128, wc = wn * 64;

  f4 acc[8][4] = {};
  const int NT = K >> 5;

  #define STAGE3(tt)                                                            \
    {                                                                           \
      const int kk = (tt) << 5;                                                 \
      const int bsel_ = (tt) & 3;                                               \
      const int r_ = tid >> 2;                                                  \
      const int cs_ = ((tid & 3) ^ ((r_ >> 1) & 3)) * 8;                        \
      gload_lds16(Ap + (size_t)(m0 + r_) * lda + kk + cs_,                      \
                  &As[bsel_][tid * 8]);                                         \
      gload_lds16(Ap + (size_t)(m0 + 128 + r_) * lda + kk + cs_,                \
                  &As[bsel_][(tid + 512) * 8]);                                 \
      gload_lds16(Bp + (size_t)(n0 + r_) * ldb + kk + cs_,                      \
                  &Bs[bsel_][tid * 8]);                                         \
      gload_lds16(Bp + (size_t)(n0 + 128 + r_) * ldb + kk + cs_,                \
                  &Bs[bsel_][(tid + 512) * 8]);                                 \
    }

  STAGE3(0);
  if (NT > 1) STAGE3(1);
  if (NT > 2) STAGE3(2);

  const int rc = (g ^ ((tl >> 1) & 3)) * 8;

  for (int t = 0; t < NT; ++t) {
    if (t + 2 < NT)      asm volatile("s_waitcnt vmcnt(8)" ::: "memory");
    else if (t + 1 < NT) asm volatile("s_waitcnt vmcnt(4)" ::: "memory");
    else                 asm volatile("s_waitcnt vmcnt(0)" ::: "memory");
    __builtin_amdgcn_sched_barrier(0);
    __builtin_amdgcn_s_barrier();
    __builtin_amdgcn_sched_barrier(0);

    if (t + 3 < NT) STAGE3(t + 3);

    const int bsel = t & 3;
    bf8 af[8], bfr[4];
    #pragma unroll
    for (int i = 0; i < 8; ++i)
      af[i] = *(const bf8*)&As[bsel][(wr + i * 16 + tl) * 32 + rc];
    #pragma unroll
    for (int i = 0; i < 4; ++i)
      bfr[i] = *(const bf8*)&Bs[bsel][(wc + i * 16 + tl) * 32 + rc];

    __builtin_amdgcn_s_setprio(1);
    #pragma unroll
    for (int mi = 0; mi < 8; ++mi)
      #pragma unroll
      for (int ni = 0; ni < 4; ++ni)
        acc[mi][ni] = __builtin_amdgcn_mfma_f32_16x16x32_bf16(af[mi], bfr[ni], acc[mi][ni], 0, 0, 0);
    __builtin_amdgcn_s_setprio(0);
  }
  #undef STAGE3

  #pragma unroll
  for (int mi = 0; mi < 8; ++mi) {
    #pragma unroll
    for (int r = 0; r < 4; ++r) {
      const int row = m0 + wr + mi * 16 + g * 4 + r;
      #pragma unroll
      for (int ni = 0; ni < 4; ++ni) {
        const int col = n0 + wc + ni * 16 + tl;
        const float v = acc[mi][ni][r];
        if constexpr (OF32) ((float*)Cp)[(size_t)row * ldc + col] = v;
        else                ((uint16_t*)Cp)[(size_t)row * ldc + col] = f2bf(v);
      }
    }
  }
}

// ---------- RoPE (in-place on bf16, pairs (d, d+64)) — used for K only ----
__global__ __launch_bounds__(256)
void eagle3_rope(uint16_t* __restrict__ x, const float* __restrict__ cs,
                 const float* __restrict__ sn, int nh, int rowlen, int total)
{
  int id = blockIdx.x * 256 + threadIdx.x;
  if (id >= total) return;
  int d = id & 63;
  int t = id >> 6;
  int head = t & (nh - 1);
  int row = t / nh;
  int s = row & 2047;
  size_t base = (size_t)row * rowlen + head * 128;
  float c = cs[s * 128 + d], si = sn[s * 128 + d];
  float x1 = bf2f(x[base + d]), x2 = bf2f(x[base + d + 64]);
  x[base + d]      = f2bf(x1 * c - x2 * si);
  x[base + d + 64] = f2bf(x2 * c + x1 * si);
}

// ---------- V transpose: [b,t,h,d] -> [b,h,d,t] ----------
__global__ __launch_bounds__(256)
void eagle3_vtrans(const uint16_t* __restrict__ V, uint16_t* __restrict__ Vt)
{
  __shared__ uint16_t T[64 * 136];
  const int tid = threadIdx.x;
  const int t0 = blockIdx.x * 64;
  const int bh = blockIdx.y;
  const int b = bh >> 3, h = bh & 7;
  {
    const int r = tid >> 2, c0 = (tid & 3) * 32;
    const uint16_t* src = V + (size_t)(b * 2048 + t0 + r) * 1024 + h * 128 + c0;
    #pragma unroll
    for (int j = 0; j < 4; ++j)
      *(bf8*)&T[r * 136 + c0 + j * 8] = *(const bf8*)(src + j * 8);
  }
  __syncthreads();
  {
    const int d = tid >> 1, tc = (tid & 1) * 32;
    uint16_t* dst = Vt + ((size_t)bh * 128 + d) * 2048 + t0 + tc;
    #pragma unroll
    for (int cc = 0; cc < 4; ++cc) {
      bf8 v;
      #pragma unroll
      for (int j = 0; j < 8; ++j) v[j] = T[(tc + cc * 8 + j) * 136 + d];
      *(bf8*)&dst[cc * 8] = v;
    }
  }
}

// ---------- causal GQA flash attention v7 ----------
// flash6 (QBLK=128, 8 waves, 2 blk/CU, 80KB LDS) + in-register RoPE on Q
// (rotate-half pair (d,d+64) = fragments (kb,kb+2) at same lane/elem) + a
// per-wave skip of the fully-masked last tile for waves 0..3.
__global__ __launch_bounds__(512, 4)
void eagle3_flash7(const uint16_t* __restrict__ Q, const uint16_t* __restrict__ Kt,
                   const uint16_t* __restrict__ Vt, uint16_t* __restrict__ O,
                   const float* __restrict__ Cst, const float* __restrict__ Snt)
{
  __shared__ __align__(16) uint16_t Ks[2][64 * 128];   // 32 KB
  __shared__ __align__(16) uint16_t Vs[2][128 * 64];   // 32 KB
  __shared__ __align__(16) uint16_t Pl[8][16 * 64];    // 16 KB (per-wave, swz)

  const int tid = threadIdx.x, lane = tid & 63, w = tid >> 6;
  const int tl = lane & 15, g = lane >> 4;

  const int bid = (int)blockIdx.x + ((int)blockIdx.y << 4) + ((int)blockIdx.z << 9);
  const int xcd = bid & 7, idx = bid >> 3;       // idx 0..127
  const int grp = xcd * 2 + (idx >> 6);          // b*8 + hkv
  const int j   = idx & 63;
  const int b = grp >> 3, hkv = grp & 7;
  const int hq = hkv * 4 + (j & 3);
  const int qt = 15 - (j >> 2);                  // 0..15, heavy first
  const int qrow0 = qt * 128 + w * 16;           // wave's 16 q-rows
  const int ntb = 2 * qt + 2;                    // 64-wide KV tiles

  // Q fragments + in-register RoPE. Lane (g,tl): row qrow0+tl, cols
  // kb*32+g*8+e. Pair (d, d+64) = (kb, kb+2) same e. cos[d]==cos[d+64].
  bf8 qf[4];
  {
    const int srow = qrow0 + tl;
    const uint16_t* qp = Q + ((size_t)(b * 2048 + srow)) * 4096 + hq * 128 + g * 8;
    #pragma unroll
    for (int kb = 0; kb < 4; ++kb) qf[kb] = *(const bf8*)(qp + kb * 32);
    const float* cp = Cst + (size_t)srow * 128 + g * 8;
    const float* sp = Snt + (size_t)srow * 128 + g * 8;
    #pragma unroll
    for (int kb = 0; kb < 2; ++kb) {
      const float4 c0 = *(const float4*)(cp + kb * 32);
      const float4 c1 = *(const float4*)(cp + kb * 32 + 4);
      const float4 s0 = *(const float4*)(sp + kb * 32);
      const float4 s1 = *(const float4*)(sp + kb * 32 + 4);
      const float cc[8] = {c0.x,c0.y,c0.z,c0.w,c1.x,c1.y,c1.z,c1.w};
      const float ss[8] = {s0.x,s0.y,s0.z,s0.w,s1.x,s1.y,s1.z,s1.w};
      #pragma unroll
      for (int e = 0; e < 8; ++e) {
        const float x1 = bf2f((uint16_t)qf[kb][e]);
        const float x2 = bf2f((uint16_t)qf[kb + 2][e]);
        qf[kb][e]     = (short)f2bf(x1 * cc[e] - x2 * ss[e]);
        qf[kb + 2][e] = (short)f2bf(x2 * cc[e] + x1 * ss[e]);
      }
    }
  }

  const uint16_t* Kbase = Kt + (size_t)b * 2048 * 1024 + hkv * 128;   // [t][128]
  const uint16_t* Vtb   = Vt + ((size_t)(b * 8 + hkv) * 128) * 2048;  // [d][t]

  // ones B-fragment: B[k][0] = 1.0 -> MFMA computes row-sums in col 0
  bf8 onesf = {};
  if (tl == 0) {
    #pragma unroll
    for (int q8 = 0; q8 < 8; ++q8) onesf[q8] = (short)0x3F80;
  }

  f4 acc[8] = {};
  f4 accl = {};                               // softmax denominators (col 0)
  float rm[4] = {-3e38f, -3e38f, -3e38f, -3e38f};
  const float KS = 0.1275174f;                // log2(e)/sqrt(128)

  #define STAGE_TILE(buf, t0s)                                                   \
    {                                                                            \
      _Pragma("unroll")                                                          \
      for (int i = 0; i < 2; ++i) {                                              \
        const int f = i * 512 + tid;                                             \
        const int r = f >> 4, c = f & 15;                                        \
        gload_lds16(Kbase + (size_t)((t0s) + r) * 1024 + ((c ^ (r & 7)) * 8),    \
                    &Ks[buf][(i * 512 + w * 64) * 8]);                           \
      }                                                                          \
      _Pragma("unroll")                                                          \
      for (int i = 0; i < 2; ++i) {                                              \
        const int f = i * 512 + tid;                                             \
        const int d = f >> 3, c = f & 7;                                         \
        gload_lds16(Vtb + (size_t)d * 2048 + (t0s) + ((c ^ (d & 7)) * 8),        \
                    &Vs[buf][(i * 512 + w * 64) * 8]);                           \
      }                                                                          \
    }

  STAGE_TILE(0, 0);

  for (int tb = 0; tb < ntb; ++tb) {
    const int cur = tb & 1;
    const int t0 = tb * 64;

    if (tb + 1 < ntb) {
      STAGE_TILE(cur ^ 1, t0 + 64);
      asm volatile("s_waitcnt vmcnt(4)" ::: "memory");   // tile tb landed
    } else {
      asm volatile("s_waitcnt vmcnt(0)" ::: "memory");
    }
    __builtin_amdgcn_sched_barrier(0);
    __builtin_amdgcn_s_barrier();

    // waves whose rows are entirely left of this tile skip compute
    // (fully-masked tile contributes p=0); staging/barriers above/below
    // are unconditional so other waves' data still lands.
    const bool active = (t0 <= qrow0 + 15);    // wave-uniform
    if (active) {
      // -- QK^T (raw scores): S(16x64) --
      f4 s[4] = {};
      __builtin_amdgcn_s_setprio(1);
      #pragma unroll
      for (int cf = 0; cf < 4; ++cf) {
        #pragma unroll
        for (int kb = 0; kb < 4; ++kb) {
          const bf8 kf = *(const bf8*)&Ks[cur][(cf * 16 + tl) * 128 +
                                              (((kb * 4 + g) ^ (tl & 7)) * 8)];
          s[cf] = __builtin_amdgcn_mfma_f32_16x16x32_bf16(qf[kb], kf, s[cf], 0, 0, 0);
        }
      }
      __builtin_amdgcn_s_setprio(0);

      // -- online softmax (raw domain; mask when tile crosses diagonal) --
      const bool edge = (t0 + 63 > qrow0);     // wave-uniform
      float p[4][4];
      #pragma unroll
      for (int r = 0; r < 4; ++r) {
        float v[4];
        #pragma unroll
        for (int cf = 0; cf < 4; ++cf) v[cf] = s[cf][r];
        if (edge) {
          const int qg = qrow0 + g * 4 + r;
          #pragma unroll
          for (int cf = 0; cf < 4; ++cf)
            if (t0 + cf * 16 + tl > qg) v[cf] = -3e38f;
        }
        float mx = fmaxf(fmaxf(v[0], v[1]), fmaxf(v[2], v[3]));
        mx = fmaxf(mx, __shfl_xor(mx, 1));
        mx = fmaxf(mx, __shfl_xor(mx, 2));
        mx = fmaxf(mx, __shfl_xor(mx, 4));
        mx = fmaxf(mx, __shfl_xor(mx, 8));
        if (mx > rm[r]) {
          const float corr = exp2f((rm[r] - mx) * KS);
          #pragma unroll
          for (int df = 0; df < 8; ++df) acc[df][r] *= corr;
          accl[r] *= corr;
          rm[r] = mx;
        }
        #pragma unroll
        for (int cf = 0; cf < 4; ++cf) p[r][cf] = exp2f((v[cf] - rm[r]) * KS);
      }

      // -- P -> LDS (XOR-swizzled [16][64]) --
      #pragma unroll
      for (int r = 0; r < 4; ++r) {
        const uint32_t pk0 = cvtpk(p[r][0], p[r][1]);
        const uint32_t pk1 = cvtpk(p[r][2], p[r][3]);
        const int row = g * 4 + r;
        const int sw = row & 7;
        uint16_t* Pw = &Pl[w][row * 64 + (tl & 7)];
        Pw[(((tl >> 3) + 0) ^ sw) * 8] = (uint16_t)pk0;
        Pw[(((tl >> 3) + 2) ^ sw) * 8] = (uint16_t)(pk0 >> 16);
        Pw[(((tl >> 3) + 4) ^ sw) * 8] = (uint16_t)pk1;
        Pw[(((tl >> 3) + 6) ^ sw) * 8] = (uint16_t)(pk1 >> 16);
      }
      const bf8 pf0 = *(const bf8*)&Pl[w][tl * 64 + ((g ^ (tl & 7)) * 8)];
      const bf8 pf1 = *(const bf8*)&Pl[w][tl * 64 + (((4 + g) ^ (tl & 7)) * 8)];

      // -- PV + denominator MFMAs --
      __builtin_amdgcn_s_setprio(1);
      accl = __builtin_amdgcn_mfma_f32_16x16x32_bf16(pf0, onesf, accl, 0, 0, 0);
      accl = __builtin_amdgcn_mfma_f32_16x16x32_bf16(pf1, onesf, accl, 0, 0, 0);
      #pragma unroll
      for (int df = 0; df < 8; ++df) {
        const int vrow = (df * 16 + tl) * 64;
        const bf8 v0 = *(const bf8*)&Vs[cur][vrow + ((g ^ (tl & 7)) * 8)];
        const bf8 v1 = *(const bf8*)&Vs[cur][vrow + (((4 + g) ^ (tl & 7)) * 8)];
        acc[df] = __builtin_amdgcn_mfma_f32_16x16x32_bf16(pf0, v0, acc[df], 0, 0, 0);
        acc[df] = __builtin_amdgcn_mfma_f32_16x16x32_bf16(pf1, v1, acc[df], 0, 0, 0);
      }
      __builtin_amdgcn_s_setprio(0);
    }

    __builtin_amdgcn_s_barrier();
  }
  #undef STAGE_TILE

  // -- normalize (l broadcast from col-0 lane of each 16-lane group) + store --
  #pragma unroll
  for (int r = 0; r < 4; ++r) {
    const float l = __shfl(accl[r], lane & 48);
    const float inv = 1.0f / l;
    const size_t ob = ((size_t)(b * 2048 + qrow0 + g * 4 + r)) * 4096 + hq * 128 + tl;
    #pragma unroll
    for (int df = 0; df < 8; ++df)
      O[ob + df * 16] = f2bf(acc[df][r] * inv);
  }
}

// ---------- launch ----------
extern "C" void kernel_launch(void* const* d_in, const int* in_sizes, int n_in,
                              void* d_out, int out_size, void* d_ws, size_t ws_size,
                              hipStream_t stream) {
  const float* hs   = (const float*)d_in[0];
  const float* cosT = (const float*)d_in[2];
  const float* sinT = (const float*)d_in[3];
  const float* Wq   = (const float*)d_in[4];
  const float* Wk   = (const float*)d_in[5];
  const float* Wv   = (const float*)d_in[6];
  const float* Wo   = (const float*)d_in[7];

  char* ws = (char*)d_ws;
  uint16_t* qb    = (uint16_t*)(ws);
  uint16_t* kbuf  = (uint16_t*)(ws + 33554432);
  uint16_t* vbuf  = (uint16_t*)(ws + 41943040);
  uint16_t* whalf = (uint16_t*)(ws + 50331648);
  uint16_t* vt    = (uint16_t*)(ws + 75497472);
  uint16_t* ctx   = (uint16_t*)(ws + 41943040);
  uint16_t* hsb   = (uint16_t*)d_out;
  uint16_t* wobf  = qb;

  const dim3 blk(256);
  const bool fullq = (ws_size >= (size_t)117440512);   // 112 MiB

  // 1) hs f32 -> bf16 (once)
  eagle3_cvt<<<dim3(2048), blk, 0, stream>>>(hs, hsb, 4194304);

  // 2) Q projection
  if (fullq) {
    eagle3_cvt<<<dim3(2048), blk, 0, stream>>>(Wq, whalf, 4194304);
    eagle3_gemm3<false><<<dim3(16, 16), dim3(512), 0, stream>>>(
        hsb, whalf, (void*)qb, 8192, 8192, 8192, 4096);
  } else {
    eagle3_cvt<<<dim3(2048), blk, 0, stream>>>(Wq, whalf, 2097152);
    eagle3_gemm2<false><<<dim3(16, 32), blk, 0, stream>>>(
        hsb, whalf, (void*)qb, 8192, 8192, 8192, 4096);
    eagle3_cvt<<<dim3(2048), blk, 0, stream>>>(Wq + 16777216, whalf, 2097152);
    eagle3_gemm2<false><<<dim3(16, 32), blk, 0, stream>>>(
        hsb, whalf, (void*)(qb + 2048), 8192, 8192, 8192, 4096);
  }

  // 3) K and V projections
  eagle3_cvt<<<dim3(2048), blk, 0, stream>>>(Wk, whalf, 1048576);
  eagle3_gemm2<false><<<dim3(8, 32), blk, 0, stream>>>(
      hsb, whalf, (void*)kbuf, 8192, 8192, 8192, 1024);
  eagle3_cvt<<<dim3(2048), blk, 0, stream>>>(Wv, whalf, 1048576);
  eagle3_gemm2<false><<<dim3(8, 32), blk, 0, stream>>>(
      hsb, whalf, (void*)vbuf, 8192, 8192, 8192, 1024);

  // 4) RoPE on K only (Q rope fused into flash7) + V transpose
  eagle3_rope<<<dim3(8192), blk, 0, stream>>>(kbuf, cosT, sinT, 8, 1024, 2097152);
  eagle3_vtrans<<<dim3(32, 16), blk, 0, stream>>>(vbuf, vt);

  // 5) causal GQA flash attention (with in-register Q RoPE) -> ctx
  eagle3_flash7<<<dim3(16, 32, 2), dim3(512), 0, stream>>>(
      qb, kbuf, vt, ctx, cosT, sinT);

  // 6) output projection: out = ctx * Wo^T (f32 out over dead hsb)
  eagle3_cvt<<<dim3(2048), blk, 0, stream>>>(Wo, wobf, 2097152);
  eagle3_gemm3<true><<<dim3(16, 16), dim3(512), 0, stream>>>(
      ctx, wobf, d_out, 4096, 4096, 4096, 4096);
}

// Round 13
// 904.150 us; speedup vs baseline: 1.1183x; 1.0342x over previous
//
#include <hip/hip_runtime.h>
#include <stdint.h>

// ---------- common types / helpers ----------
typedef __attribute__((ext_vector_type(8))) short bf8;   // 8 x bf16 (4 VGPRs)
typedef __attribute__((ext_vector_type(4))) float f4;    // MFMA accumulator

__device__ __forceinline__ float bf2f(uint16_t u) {
  union { unsigned i; float f; } v; v.i = ((unsigned)u) << 16; return v.f;
}
__device__ __forceinline__ uint16_t f2bf(float f) {
  union { float f; unsigned i; } v; v.f = f;
  unsigned r = v.i + 0x7fffu + ((v.i >> 16) & 1u);   // RTNE
  return (uint16_t)(r >> 16);
}
__device__ __forceinline__ bf8 cvt8(float4 a, float4 b) {
  bf8 r;
  r[0]=(short)f2bf(a.x); r[1]=(short)f2bf(a.y); r[2]=(short)f2bf(a.z); r[3]=(short)f2bf(a.w);
  r[4]=(short)f2bf(b.x); r[5]=(short)f2bf(b.y); r[6]=(short)f2bf(b.z); r[7]=(short)f2bf(b.w);
  return r;
}
// packed f32x2 -> bf16x2 (RNE); dst.lo = cvt(a), dst.hi = cvt(b)  [T12 recipe]
__device__ __forceinline__ uint32_t cvtpk(float a, float b) {
  uint32_t r;
  asm("v_cvt_pk_bf16_f32 %0, %1, %2" : "=v"(r) : "v"(a), "v"(b));
  return r;
}

// async global->LDS, 16B per lane, wave-uniform LDS base + lane*16
__device__ __forceinline__ void gload_lds16(const void* g, void* l) {
  __builtin_amdgcn_global_load_lds(
      (const __attribute__((address_space(1))) uint32_t*)(uintptr_t)g,
      (__attribute__((address_space(3))) uint32_t*)(uint32_t)(uintptr_t)l,
      16, 0, 0);
}

// ---------- f32 -> bf16 bulk convert ----------
__global__ __launch_bounds__(256)
void eagle3_cvt(const float* __restrict__ src, uint16_t* __restrict__ dst, int n8)
{
  int i = blockIdx.x * 256 + threadIdx.x;
  const int stride = gridDim.x * 256;
  for (; i < n8; i += stride) {
    const float4 a = ((const float4*)src)[i * 2];
    const float4 b = ((const float4*)src)[i * 2 + 1];
    ((bf8*)dst)[i] = cvt8(a, b);
  }
}

// ---------- GEMM v2 (128x128, m97 structure) : C = A * B^T, bf16 ----------
template<bool OF32>
__global__ __launch_bounds__(256)
void eagle3_gemm2(const uint16_t* __restrict__ Ap, const uint16_t* __restrict__ Bp,
                  void* __restrict__ Cp, int K, int lda, int ldb, int ldc)
{
  __shared__ __align__(16) uint16_t As[128 * 32];
  __shared__ __align__(16) uint16_t Bs[128 * 32];

  const int nwg = gridDim.x * gridDim.y;
  const int bid = blockIdx.y * gridDim.x + blockIdx.x;
  const int qq = nwg >> 3;
  const int sw = (bid & 7) * qq + (bid >> 3);
  const int bx = sw % gridDim.x, by = sw / gridDim.x;
  const int m0 = by * 128, n0 = bx * 128;

  const int tid = threadIdx.x, lane = tid & 63, w = tid >> 6;
  const int tl = lane & 15, g = lane >> 4;
  const int wr = (w >> 1) * 64, wc = (w & 1) * 64;

  f4 acc[4][4] = {};

  for (int k0 = 0; k0 < K; k0 += 32) {
    __syncthreads();
    #pragma unroll
    for (int i = 0; i < 2; ++i) {
      const int o = (w * 2 + i) * 1024 + lane * 16;
      const int r = o >> 6;
      const int u = (((o >> 4) & 3) ^ ((r >> 1) & 3)) * 8;
      gload_lds16(Ap + (size_t)(m0 + r) * lda + k0 + u, &As[(w * 2 + i) * 512]);
    }
    #pragma unroll
    for (int i = 0; i < 2; ++i) {
      const int o = (w * 2 + i) * 1024 + lane * 16;
      const int r = o >> 6;
      const int u = (((o >> 4) & 3) ^ ((r >> 1) & 3)) * 8;
      gload_lds16(Bp + (size_t)(n0 + r) * ldb + k0 + u, &Bs[(w * 2 + i) * 512]);
    }
    __syncthreads();

    bf8 af[4], bf_[4];
    #pragma unroll
    for (int i = 0; i < 4; ++i) {
      const int ar = wr + i * 16 + tl;
      const int br = wc + i * 16 + tl;
      af[i]  = *(const bf8*)&As[ar * 32 + ((g ^ ((ar >> 1) & 3)) * 8)];
      bf_[i] = *(const bf8*)&Bs[br * 32 + ((g ^ ((br >> 1) & 3)) * 8)];
    }
    #pragma unroll
    for (int mi = 0; mi < 4; ++mi)
      #pragma unroll
      for (int ni = 0; ni < 4; ++ni)
        acc[mi][ni] = __builtin_amdgcn_mfma_f32_16x16x32_bf16(af[mi], bf_[ni], acc[mi][ni], 0, 0, 0);
  }

  #pragma unroll
  for (int mi = 0; mi < 4; ++mi) {
    #pragma unroll
    for (int r = 0; r < 4; ++r) {
      const int row = m0 + wr + mi * 16 + g * 4 + r;
      #pragma unroll
      for (int ni = 0; ni < 4; ++ni) {
        const int col = n0 + wc + ni * 16 + tl;
        const float v = acc[mi][ni][r];
        if constexpr (OF32) ((float*)Cp)[(size_t)row * ldc + col] = v;
        else                ((uint16_t*)Cp)[(size_t)row * ldc + col] = f2bf(v);
      }
    }
  }
}

// ---------- GEMM v5 (256x256, BK=64, 8-phase m201-style schedule) ----------
// 512 threads = 8 waves (2M x 4N), per-wave 128x64 out (acc 8x4).
// LDS: [A|B][2 dbuf slots][2 halves][128x64] = 128 KB. Iteration i computes
// K-tiles T0=2i (slot0, phases p0-p3) and T1=2i+1 (slot1, p4-p7); each phase:
// {8 A-reads or 4 B-reads ; 1 half-tile stage (2 gloads) ; barrier ;
//  lgkmcnt(0) ; 16 MFMA ; [counted vmcnt gate] ; barrier}.
// Staging placement vs read-completion table (all verified):
//   p0:Ah0(T1) p1:Ah1(T1) p2:Bh0(T0+2) p3:Bh1(T0+2)
//   p4:Ah0(T0+2) p5:Ah1(T0+2) p6:Bh0(T1+2) p7:Bh1(T1+2)
// Read gates (vmcnt before closing barrier): p2:6, p3:4, p6:6, p7:4
// (last iteration: 4, 0, -, -). Row-XOR chunk swizzle c^=(r&7) both sides.
template<bool OF32>
__global__ __launch_bounds__(512, 2)
void eagle3_gemm5(const uint16_t* __restrict__ Ap, const uint16_t* __restrict__ Bp,
                  void* __restrict__ Cp, int K, int lda, int ldb, int ldc)
{
  __shared__ __align__(16) uint16_t As[2][2][128 * 64];
  __shared__ __align__(16) uint16_t Bs[2][2][128 * 64];

  int bx, by;
  const int bid = blockIdx.y * gridDim.x + blockIdx.x;
  if (gridDim.x == 16 && gridDim.y == 16) {
    const int x = bid & 7, j = bid >> 3;     // XCD x, local block j (0..31)
    by = (x >> 1) * 4 + (j >> 3);            // 4 m-panels per XCD
    bx = (x & 1) * 8 + (j & 7);              // 8 n-panels per XCD
  } else {
    const int nwg = gridDim.x * gridDim.y;
    const int qq = nwg >> 3;
    const int sw = (bid & 7) * qq + (bid >> 3);
    bx = sw % gridDim.x; by = sw / gridDim.x;
  }
  const int m0 = by * 256, n0 = bx * 256;

  const int tid = threadIdx.x, lane = tid & 63;
  const int tl = lane & 15, g = lane >> 4;
  const int w = tid >> 6;                 // 0..7
  const int wm = w >> 2, wn = w & 3;      // 2 x 4
  const int bhf = wn >> 1;                // B half this wave reads
  const int bl0 = (wn & 1) * 64;          // local col base inside the half

  f4 acc[8][4] = {};
  const int NI = K >> 7;                  // iterations (2 K-tiles each)

  // staging: thread t writes chunks j=t (rows 0-63) and j=t+512 (rows 64-127)
  // of a 128x64 half-tile; global source chunk pre-swizzled by (row&7).
  const int jr = tid >> 3;
  const int jc = ((tid & 7) ^ (jr & 7)) * 8;
  #define STG_A(slot, h, tt)                                                    \
    { const int kk_ = (tt) << 6;                                                \
      gload_lds16(Ap + (size_t)(m0 + (h)*128 + jr) * lda + kk_ + jc,            \
                  &As[slot][h][tid * 8]);                                       \
      gload_lds16(Ap + (size_t)(m0 + (h)*128 + 64 + jr) * lda + kk_ + jc,       \
                  &As[slot][h][(tid + 512) * 8]); }
  #define STG_B(slot, h, tt)                                                    \
    { const int kk_ = (tt) << 6;                                                \
      gload_lds16(Bp + (size_t)(n0 + (h)*128 + jr) * ldb + kk_ + jc,            \
                  &Bs[slot][h][tid * 8]);                                       \
      gload_lds16(Bp + (size_t)(n0 + (h)*128 + 64 + jr) * ldb + kk_ + jc,       \
                  &Bs[slot][h][(tid + 512) * 8]); }

  const int rk0 = ((0 + g) ^ (tl & 7)) * 8;   // k-half 0 read chunk
  const int rk1 = ((4 + g) ^ (tl & 7)) * 8;   // k-half 1 read chunk

  bf8 af[8], b0[4], b1[4];
  #define READ_A(slot, rh)                                                      \
    { _Pragma("unroll")                                                         \
      for (int m_ = 0; m_ < 4; ++m_) {                                          \
        const int R_ = (rh)*64 + m_*16 + tl;                                    \
        af[m_*2]   = *(const bf8*)&As[slot][wm][R_*64 + rk0];                   \
        af[m_*2+1] = *(const bf8*)&As[slot][wm][R_*64 + rk1];                   \
      } }
  #define READ_B(slot, ch, dst)                                                 \
    { _Pragma("unroll")                                                         \
      for (int c_ = 0; c_ < 2; ++c_) {                                          \
        const int R_ = bl0 + (ch)*32 + c_*16 + tl;                              \
        dst[c_*2]   = *(const bf8*)&Bs[slot][bhf][R_*64 + rk0];                 \
        dst[c_*2+1] = *(const bf8*)&Bs[slot][bhf][R_*64 + rk1];                 \
      } }
  #define MID_SYNC                                                              \
    __builtin_amdgcn_sched_barrier(0);                                          \
    __builtin_amdgcn_s_barrier();                                               \
    asm volatile("s_waitcnt lgkmcnt(0)" ::: "memory");                          \
    __builtin_amdgcn_sched_barrier(0);
  #define CLOSE_BAR                                                             \
    __builtin_amdgcn_sched_barrier(0);                                          \
    __builtin_amdgcn_s_barrier();                                               \
    __builtin_amdgcn_sched_barrier(0);
  #define MFMA16(rh, ch, bsrc)                                                  \
    { __builtin_amdgcn_s_setprio(1);                                            \
      _Pragma("unroll")                                                         \
      for (int m_ = 0; m_ < 4; ++m_) {                                          \
        _Pragma("unroll")                                                       \
        for (int c_ = 0; c_ < 2; ++c_) {                                        \
          acc[(rh)*4+m_][(ch)*2+c_] = __builtin_amdgcn_mfma_f32_16x16x32_bf16(  \
              af[m_*2],   bsrc[c_*2],   acc[(rh)*4+m_][(ch)*2+c_], 0, 0, 0);    \
          acc[(rh)*4+m_][(ch)*2+c_] = __builtin_amdgcn_mfma_f32_16x16x32_bf16(  \
              af[m_*2+1], bsrc[c_*2+1], acc[(rh)*4+m_][(ch)*2+c_], 0, 0, 0);    \
        } }                                                                     \
      __builtin_amdgcn_s_setprio(0); }

  // ---- prologue: tile0 fully (8 loads), tile1 B halves (4 loads) ----
  STG_A(0, 0, 0); STG_A(0, 1, 0); STG_B(0, 0, 0); STG_B(0, 1, 0);
  STG_B(1, 0, 1); STG_B(1, 1, 1);
  asm volatile("s_waitcnt vmcnt(4)" ::: "memory");   // tile 0 landed
  CLOSE_BAR;
  READ_B(0, 0, b0);                                  // T0=0, ch0 (prev-p7 role)

  for (int i = 0; i < NI; ++i) {
    const int T1 = 2 * i + 1;
    const bool more = (i + 1 < NI);

    // p0: T0(rh0,ch0); stage Ah0(T1)
    READ_A(0, 0);
    STG_A(1, 0, T1);
    MID_SYNC; MFMA16(0, 0, b0); CLOSE_BAR;

    // p1: T0(rh0,ch1); stage Ah1(T1)
    READ_B(0, 1, b1);
    STG_A(1, 1, T1);
    MID_SYNC; MFMA16(0, 1, b1); CLOSE_BAR;

    // p2: T0(rh1,ch0); stage Bh0(T0+2); gate p3's B(T1) read
    READ_A(0, 1);
    if (more) STG_B(0, 0, T1 + 1);
    MID_SYNC; MFMA16(1, 0, b0);
    if (more) { asm volatile("s_waitcnt vmcnt(6)" ::: "memory"); }
    else      { asm volatile("s_waitcnt vmcnt(4)" ::: "memory"); }
    CLOSE_BAR;

    // p3: T0(rh1,ch1); read B(T1,ch0); stage Bh1(T0+2); gate p4's A(T1)
    READ_B(1, 0, b0);
    if (more) STG_B(0, 1, T1 + 1);
    MID_SYNC; MFMA16(1, 1, b1);
    if (more) { asm volatile("s_waitcnt vmcnt(4)" ::: "memory"); }
    else      { asm volatile("s_waitcnt vmcnt(0)" ::: "memory"); }
    CLOSE_BAR;

    // p4: T1(rh0,ch0); stage Ah0(T0+2)
    READ_A(1, 0);
    if (more) STG_A(0, 0, T1 + 1);
    MID_SYNC; MFMA16(0, 0, b0); CLOSE_BAR;

    // p5: T1(rh0,ch1); stage Ah1(T0+2)
    READ_B(1, 1, b1);
    if (more) STG_A(0, 1, T1 + 1);
    MID_SYNC; MFMA16(0, 1, b1); CLOSE_BAR;

    // p6: T1(rh1,ch0); stage Bh0(T1+2); gate p7's B(T0+2) read
    READ_A(1, 1);
    if (more) STG_B(1, 0, T1 + 2);
    MID_SYNC; MFMA16(1, 0, b0);
    if (more) { asm volatile("s_waitcnt vmcnt(6)" ::: "memory"); }
    CLOSE_BAR;

    // p7: T1(rh1,ch1); read B(T0+2,ch0); stage Bh1(T1+2); gate next p0's A
    if (more) { READ_B(0, 0, b0); STG_B(1, 1, T1 + 2); }
    MID_SYNC; MFMA16(1, 1, b1);
    if (more) { asm volatile("s_waitcnt vmcnt(4)" ::: "memory"); }
    CLOSE_BAR;
  }
  #undef STG_A
  #undef STG_B
  #undef READ_A
  #undef READ_B
  #undef MID_SYNC
  #undef CLOSE_BAR
  #undef MFMA16

  // epilogue: C/D layout col=lane&15, row=(lane>>4)*4+reg
  const int wr = wm * 128, wc = wn * 64;
  #pragma unroll
  for (int mi = 0; mi < 8; ++mi) {
    #pragma unroll
    for (int r = 0; r < 4; ++r) {
      const int row = m0 + wr + mi * 16 + g * 4 + r;
      #pragma unroll
      for (int ni = 0; ni < 4; ++ni) {
        const int col = n0 + wc + ni * 16 + tl;
        const float v = acc[mi][ni][r];
        if constexpr (OF32) ((float*)Cp)[(size_t)row * ldc + col] = v;
        else                ((uint16_t*)Cp)[(size_t)row * ldc + col] = f2bf(v);
      }
    }
  }
}

// ---------- RoPE (in-place on bf16, pairs (d, d+64)) — used for K only ----
__global__ __launch_bounds__(256)
void eagle3_rope(uint16_t* __restrict__ x, const float* __restrict__ cs,
                 const float* __restrict__ sn, int nh, int rowlen, int total)
{
  int id = blockIdx.x * 256 + threadIdx.x;
  if (id >= total) return;
  int d = id & 63;
  int t = id >> 6;
  int head = t & (nh - 1);
  int row = t / nh;
  int s = row & 2047;
  size_t base = (size_t)row * rowlen + head * 128;
  float c = cs[s * 128 + d], si = sn[s * 128 + d];
  float x1 = bf2f(x[base + d]), x2 = bf2f(x[base + d + 64]);
  x[base + d]      = f2bf(x1 * c - x2 * si);
  x[base + d + 64] = f2bf(x2 * c + x1 * si);
}

// ---------- V transpose: [b,t,h,d] -> [b,h,d,t] ----------
__global__ __launch_bounds__(256)
void eagle3_vtrans(const uint16_t* __restrict__ V, uint16_t* __restrict__ Vt)
{
  __shared__ uint16_t T[64 * 136];
  const int tid = threadIdx.x;
  const int t0 = blockIdx.x * 64;
  const int bh = blockIdx.y;
  const int b = bh >> 3, h = bh & 7;
  {
    const int r = tid >> 2, c0 = (tid & 3) * 32;
    const uint16_t* src = V + (size_t)(b * 2048 + t0 + r) * 1024 + h * 128 + c0;
    #pragma unroll
    for (int j = 0; j < 4; ++j)
      *(bf8*)&T[r * 136 + c0 + j * 8] = *(const bf8*)(src + j * 8);
  }
  __syncthreads();
  {
    const int d = tid >> 1, tc = (tid & 1) * 32;
    uint16_t* dst = Vt + ((size_t)bh * 128 + d) * 2048 + t0 + tc;
    #pragma unroll
    for (int cc = 0; cc < 4; ++cc) {
      bf8 v;
      #pragma unroll
      for (int j = 0; j < 8; ++j) v[j] = T[(tc + cc * 8 + j) * 136 + d];
      *(bf8*)&dst[cc * 8] = v;
    }
  }
}

// ---------- causal GQA flash attention v7 (unchanged from round 12) ----------
__global__ __launch_bounds__(512, 4)
void eagle3_flash7(const uint16_t* __restrict__ Q, const uint16_t* __restrict__ Kt,
                   const uint16_t* __restrict__ Vt, uint16_t* __restrict__ O,
                   const float* __restrict__ Cst, const float* __restrict__ Snt)
{
  __shared__ __align__(16) uint16_t Ks[2][64 * 128];   // 32 KB
  __shared__ __align__(16) uint16_t Vs[2][128 * 64];   // 32 KB
  __shared__ __align__(16) uint16_t Pl[8][16 * 64];    // 16 KB (per-wave, swz)

  const int tid = threadIdx.x, lane = tid & 63, w = tid >> 6;
  const int tl = lane & 15, g = lane >> 4;

  const int bid = (int)blockIdx.x + ((int)blockIdx.y << 4) + ((int)blockIdx.z << 9);
  const int xcd = bid & 7, idx = bid >> 3;       // idx 0..127
  const int grp = xcd * 2 + (idx >> 6);          // b*8 + hkv
  const int j   = idx & 63;
  const int b = grp >> 3, hkv = grp & 7;
  const int hq = hkv * 4 + (j & 3);
  const int qt = 15 - (j >> 2);                  // 0..15, heavy first
  const int qrow0 = qt * 128 + w * 16;           // wave's 16 q-rows
  const int ntb = 2 * qt + 2;                    // 64-wide KV tiles

  bf8 qf[4];
  {
    const int srow = qrow0 + tl;
    const uint16_t* qp = Q + ((size_t)(b * 2048 + srow)) * 4096 + hq * 128 + g * 8;
    #pragma unroll
    for (int kb = 0; kb < 4; ++kb) qf[kb] = *(const bf8*)(qp + kb * 32);
    const float* cp = Cst + (size_t)srow * 128 + g * 8;
    const float* sp = Snt + (size_t)srow * 128 + g * 8;
    #pragma unroll
    for (int kb = 0; kb < 2; ++kb) {
      const float4 c0 = *(const float4*)(cp + kb * 32);
      const float4 c1 = *(const float4*)(cp + kb * 32 + 4);
      const float4 s0 = *(const float4*)(sp + kb * 32);
      const float4 s1 = *(const float4*)(sp + kb * 32 + 4);
      const float cc[8] = {c0.x,c0.y,c0.z,c0.w,c1.x,c1.y,c1.z,c1.w};
      const float ss[8] = {s0.x,s0.y,s0.z,s0.w,s1.x,s1.y,s1.z,s1.w};
      #pragma unroll
      for (int e = 0; e < 8; ++e) {
        const float x1 = bf2f((uint16_t)qf[kb][e]);
        const float x2 = bf2f((uint16_t)qf[kb + 2][e]);
        qf[kb][e]     = (short)f2bf(x1 * cc[e] - x2 * ss[e]);
        qf[kb + 2][e] = (short)f2bf(x2 * cc[e] + x1 * ss[e]);
      }
    }
  }

  const uint16_t* Kbase = Kt + (size_t)b * 2048 * 1024 + hkv * 128;   // [t][128]
  const uint16_t* Vtb   = Vt + ((size_t)(b * 8 + hkv) * 128) * 2048;  // [d][t]

  bf8 onesf = {};
  if (tl == 0) {
    #pragma unroll
    for (int q8 = 0; q8 < 8; ++q8) onesf[q8] = (short)0x3F80;
  }

  f4 acc[8] = {};
  f4 accl = {};                               // softmax denominators (col 0)
  float rm[4] = {-3e38f, -3e38f, -3e38f, -3e38f};
  const float KS = 0.1275174f;                // log2(e)/sqrt(128)

  #define STAGE_TILE(buf, t0s)                                                   \
    {                                                                            \
      _Pragma("unroll")                                                          \
      for (int i = 0; i < 2; ++i) {                                              \
        const int f = i * 512 + tid;                                             \
        const int r = f >> 4, c = f & 15;                                        \
        gload_lds16(Kbase + (size_t)((t0s) + r) * 1024 + ((c ^ (r & 7)) * 8),    \
                    &Ks[buf][(i * 512 + w * 64) * 8]);                           \
      }                                                                          \
      _Pragma("unroll")                                                          \
      for (int i = 0; i < 2; ++i) {                                              \
        const int f = i * 512 + tid;                                             \
        const int d = f >> 3, c = f & 7;                                         \
        gload_lds16(Vtb + (size_t)d * 2048 + (t0s) + ((c ^ (d & 7)) * 8),        \
                    &Vs[buf][(i * 512 + w * 64) * 8]);                           \
      }                                                                          \
    }

  STAGE_TILE(0, 0);

  for (int tb = 0; tb < ntb; ++tb) {
    const int cur = tb & 1;
    const int t0 = tb * 64;

    if (tb + 1 < ntb) {
      STAGE_TILE(cur ^ 1, t0 + 64);
      asm volatile("s_waitcnt vmcnt(4)" ::: "memory");   // tile tb landed
    } else {
      asm volatile("s_waitcnt vmcnt(0)" ::: "memory");
    }
    __builtin_amdgcn_sched_barrier(0);
    __builtin_amdgcn_s_barrier();

    const bool active = (t0 <= qrow0 + 15);    // wave-uniform
    if (active) {
      // -- QK^T (raw scores): S(16x64) --
      f4 s[4] = {};
      __builtin_amdgcn_s_setprio(1);
      #pragma unroll
      for (int cf = 0; cf < 4; ++cf) {
        #pragma unroll
        for (int kb = 0; kb < 4; ++kb) {
          const bf8 kf = *(const bf8*)&Ks[cur][(cf * 16 + tl) * 128 +
                                              (((kb * 4 + g) ^ (tl & 7)) * 8)];
          s[cf] = __builtin_amdgcn_mfma_f32_16x16x32_bf16(qf[kb], kf, s[cf], 0, 0, 0);
        }
      }
      __builtin_amdgcn_s_setprio(0);

      const bool edge = (t0 + 63 > qrow0);     // wave-uniform
      float p[4][4];
      #pragma unroll
      for (int r = 0; r < 4; ++r) {
        float v[4];
        #pragma unroll
        for (int cf = 0; cf < 4; ++cf) v[cf] = s[cf][r];
        if (edge) {
          const int qg = qrow0 + g * 4 + r;
          #pragma unroll
          for (int cf = 0; cf < 4; ++cf)
            if (t0 + cf * 16 + tl > qg) v[cf] = -3e38f;
        }
        float mx = fmaxf(fmaxf(v[0], v[1]), fmaxf(v[2], v[3]));
        mx = fmaxf(mx, __shfl_xor(mx, 1));
        mx = fmaxf(mx, __shfl_xor(mx, 2));
        mx = fmaxf(mx, __shfl_xor(mx, 4));
        mx = fmaxf(mx, __shfl_xor(mx, 8));
        if (mx > rm[r]) {
          const float corr = exp2f((rm[r] - mx) * KS);
          #pragma unroll
          for (int df = 0; df < 8; ++df) acc[df][r] *= corr;
          accl[r] *= corr;
          rm[r] = mx;
        }
        #pragma unroll
        for (int cf = 0; cf < 4; ++cf) p[r][cf] = exp2f((v[cf] - rm[r]) * KS);
      }

      #pragma unroll
      for (int r = 0; r < 4; ++r) {
        const uint32_t pk0 = cvtpk(p[r][0], p[r][1]);
        const uint32_t pk1 = cvtpk(p[r][2], p[r][3]);
        const int row = g * 4 + r;
        const int sw = row & 7;
        uint16_t* Pw = &Pl[w][row * 64 + (tl & 7)];
        Pw[(((tl >> 3) + 0) ^ sw) * 8] = (uint16_t)pk0;
        Pw[(((tl >> 3) + 2) ^ sw) * 8] = (uint16_t)(pk0 >> 16);
        Pw[(((tl >> 3) + 4) ^ sw) * 8] = (uint16_t)pk1;
        Pw[(((tl >> 3) + 6) ^ sw) * 8] = (uint16_t)(pk1 >> 16);
      }
      const bf8 pf0 = *(const bf8*)&Pl[w][tl * 64 + ((g ^ (tl & 7)) * 8)];
      const bf8 pf1 = *(const bf8*)&Pl[w][tl * 64 + (((4 + g) ^ (tl & 7)) * 8)];

      __builtin_amdgcn_s_setprio(1);
      accl = __builtin_amdgcn_mfma_f32_16x16x32_bf16(pf0, onesf, accl, 0, 0, 0);
      accl = __builtin_amdgcn_mfma_f32_16x16x32_bf16(pf1, onesf, accl, 0, 0, 0);
      #pragma unroll
      for (int df = 0; df < 8; ++df) {
        const int vrow = (df * 16 + tl) * 64;
        const bf8 v0 = *(const bf8*)&Vs[cur][vrow + ((g ^ (tl & 7)) * 8)];
        const bf8 v1 = *(const bf8*)&Vs[cur][vrow + (((4 + g) ^ (tl & 7)) * 8)];
        acc[df] = __builtin_amdgcn_mfma_f32_16x16x32_bf16(pf0, v0, acc[df], 0, 0, 0);
        acc[df] = __builtin_amdgcn_mfma_f32_16x16x32_bf16(pf1, v1, acc[df], 0, 0, 0);
      }
      __builtin_amdgcn_s_setprio(0);
    }

    __builtin_amdgcn_s_barrier();
  }
  #undef STAGE_TILE

  #pragma unroll
  for (int r = 0; r < 4; ++r) {
    const float l = __shfl(accl[r], lane & 48);
    const float inv = 1.0f / l;
    const size_t ob = ((size_t)(b * 2048 + qrow0 + g * 4 + r)) * 4096 + hq * 128 + tl;
    #pragma unroll
    for (int df = 0; df < 8; ++df)
      O[ob + df * 16] = f2bf(acc[df][r] * inv);
  }
}

// ---------- launch ----------
extern "C" void kernel_launch(void* const* d_in, const int* in_sizes, int n_in,
                              void* d_out, int out_size, void* d_ws, size_t ws_size,
                              hipStream_t stream) {
  const float* hs   = (const float*)d_in[0];
  const float* cosT = (const float*)d_in[2];
  const float* sinT = (const float*)d_in[3];
  const float* Wq   = (const float*)d_in[4];
  const float* Wk   = (const float*)d_in[5];
  const float* Wv   = (const float*)d_in[6];
  const float* Wo   = (const float*)d_in[7];

  char* ws = (char*)d_ws;
  uint16_t* qb    = (uint16_t*)(ws);
  uint16_t* kbuf  = (uint16_t*)(ws + 33554432);
  uint16_t* vbuf  = (uint16_t*)(ws + 41943040);
  uint16_t* whalf = (uint16_t*)(ws + 50331648);
  uint16_t* vt    = (uint16_t*)(ws + 75497472);
  uint16_t* ctx   = (uint16_t*)(ws + 41943040);
  uint16_t* hsb   = (uint16_t*)d_out;
  uint16_t* wobf  = qb;

  const dim3 blk(256);
  const bool fullq = (ws_size >= (size_t)117440512);   // 112 MiB

  // 1) hs f32 -> bf16 (once)
  eagle3_cvt<<<dim3(2048), blk, 0, stream>>>(hs, hsb, 4194304);

  // 2) Q projection
  if (fullq) {
    eagle3_cvt<<<dim3(2048), blk, 0, stream>>>(Wq, whalf, 4194304);
    eagle3_gemm5<false><<<dim3(16, 16), dim3(512), 0, stream>>>(
        hsb, whalf, (void*)qb, 8192, 8192, 8192, 4096);
  } else {
    eagle3_cvt<<<dim3(2048), blk, 0, stream>>>(Wq, whalf, 2097152);
    eagle3_gemm2<false><<<dim3(16, 32), blk, 0, stream>>>(
        hsb, whalf, (void*)qb, 8192, 8192, 8192, 4096);
    eagle3_cvt<<<dim3(2048), blk, 0, stream>>>(Wq + 16777216, whalf, 2097152);
    eagle3_gemm2<false><<<dim3(16, 32), blk, 0, stream>>>(
        hsb, whalf, (void*)(qb + 2048), 8192, 8192, 8192, 4096);
  }

  // 3) K and V projections
  eagle3_cvt<<<dim3(2048), blk, 0, stream>>>(Wk, whalf, 1048576);
  eagle3_gemm2<false><<<dim3(8, 32), blk, 0, stream>>>(
      hsb, whalf, (void*)kbuf, 8192, 8192, 8192, 1024);
  eagle3_cvt<<<dim3(2048), blk, 0, stream>>>(Wv, whalf, 1048576);
  eagle3_gemm2<false><<<dim3(8, 32), blk, 0, stream>>>(
      hsb, whalf, (void*)vbuf, 8192, 8192, 8192, 1024);

  // 4) RoPE on K only (Q rope fused into flash7) + V transpose
  eagle3_rope<<<dim3(8192), blk, 0, stream>>>(kbuf, cosT, sinT, 8, 1024, 2097152);
  eagle3_vtrans<<<dim3(32, 16), blk, 0, stream>>>(vbuf, vt);

  // 5) causal GQA flash attention (with in-register Q RoPE) -> ctx
  eagle3_flash7<<<dim3(16, 32, 2), dim3(512), 0, stream>>>(
      qb, kbuf, vt, ctx, cosT, sinT);

  // 6) output projection: out = ctx * Wo^T (f32 out over dead hsb)
  eagle3_cvt<<<dim3(2048), blk, 0, stream>>>(Wo, wobf, 2097152);
  eagle3_gemm5<true><<<dim3(16, 16), dim3(512), 0, stream>>>(
      ctx, wobf, d_out, 4096, 4096, 4096, 4096);
}

// Round 14
// 746.627 us; speedup vs baseline: 1.3542x; 1.2110x over previous
//
#include <hip/hip_runtime.h>
#include <stdint.h>

// ---------- common types / helpers ----------
typedef __attribute__((ext_vector_type(8))) short bf8;   // 8 x bf16 (4 VGPRs)
typedef __attribute__((ext_vector_type(4))) float f4;    // MFMA accumulator

__device__ __forceinline__ float bf2f(uint16_t u) {
  union { unsigned i; float f; } v; v.i = ((unsigned)u) << 16; return v.f;
}
__device__ __forceinline__ uint16_t f2bf(float f) {
  union { float f; unsigned i; } v; v.f = f;
  unsigned r = v.i + 0x7fffu + ((v.i >> 16) & 1u);   // RTNE
  return (uint16_t)(r >> 16);
}
__device__ __forceinline__ bf8 cvt8(float4 a, float4 b) {
  bf8 r;
  r[0]=(short)f2bf(a.x); r[1]=(short)f2bf(a.y); r[2]=(short)f2bf(a.z); r[3]=(short)f2bf(a.w);
  r[4]=(short)f2bf(b.x); r[5]=(short)f2bf(b.y); r[6]=(short)f2bf(b.z); r[7]=(short)f2bf(b.w);
  return r;
}
// packed f32x2 -> bf16x2 (RNE); dst.lo = cvt(a), dst.hi = cvt(b)  [T12 recipe]
__device__ __forceinline__ uint32_t cvtpk(float a, float b) {
  uint32_t r;
  asm("v_cvt_pk_bf16_f32 %0, %1, %2" : "=v"(r) : "v"(a), "v"(b));
  return r;
}

// async global->LDS, 16B per lane, wave-uniform LDS base + lane*16
__device__ __forceinline__ void gload_lds16(const void* g, void* l) {
  __builtin_amdgcn_global_load_lds(
      (const __attribute__((address_space(1))) uint32_t*)(uintptr_t)g,
      (__attribute__((address_space(3))) uint32_t*)(uint32_t)(uintptr_t)l,
      16, 0, 0);
}

// ---------- f32 -> bf16 bulk convert ----------
__global__ __launch_bounds__(256)
void eagle3_cvt(const float* __restrict__ src, uint16_t* __restrict__ dst, int n8)
{
  int i = blockIdx.x * 256 + threadIdx.x;
  const int stride = gridDim.x * 256;
  for (; i < n8; i += stride) {
    const float4 a = ((const float4*)src)[i * 2];
    const float4 b = ((const float4*)src)[i * 2 + 1];
    ((bf8*)dst)[i] = cvt8(a, b);
  }
}

// ---------- dual f32 -> bf16 convert (two src/dst pairs, one launch) ----------
__global__ __launch_bounds__(256)
void eagle3_cvt2(const float* __restrict__ s1, uint16_t* __restrict__ d1, int n1,
                 const float* __restrict__ s2, uint16_t* __restrict__ d2, int n2)
{
  int i = blockIdx.x * 256 + threadIdx.x;
  const int stride = gridDim.x * 256;
  const int tot = n1 + n2;
  for (; i < tot; i += stride) {
    const float* src; uint16_t* dst; int j;
    if (i < n1) { src = s1; dst = d1; j = i; }
    else        { src = s2; dst = d2; j = i - n1; }
    const float4 a = ((const float4*)src)[j * 2];
    const float4 b = ((const float4*)src)[j * 2 + 1];
    ((bf8*)dst)[j] = cvt8(a, b);
  }
}

// ---------- GEMM v2 (128x128, m97 structure) : C = A * B^T, bf16 ----------
template<bool OF32>
__global__ __launch_bounds__(256)
void eagle3_gemm2(const uint16_t* __restrict__ Ap, const uint16_t* __restrict__ Bp,
                  void* __restrict__ Cp, int K, int lda, int ldb, int ldc)
{
  __shared__ __align__(16) uint16_t As[128 * 32];
  __shared__ __align__(16) uint16_t Bs[128 * 32];

  const int nwg = gridDim.x * gridDim.y;
  const int bid = blockIdx.y * gridDim.x + blockIdx.x;
  const int qq = nwg >> 3;
  const int sw = (bid & 7) * qq + (bid >> 3);
  const int bx = sw % gridDim.x, by = sw / gridDim.x;
  const int m0 = by * 128, n0 = bx * 128;

  const int tid = threadIdx.x, lane = tid & 63, w = tid >> 6;
  const int tl = lane & 15, g = lane >> 4;
  const int wr = (w >> 1) * 64, wc = (w & 1) * 64;

  f4 acc[4][4] = {};

  for (int k0 = 0; k0 < K; k0 += 32) {
    __syncthreads();
    #pragma unroll
    for (int i = 0; i < 2; ++i) {
      const int o = (w * 2 + i) * 1024 + lane * 16;
      const int r = o >> 6;
      const int u = (((o >> 4) & 3) ^ ((r >> 1) & 3)) * 8;
      gload_lds16(Ap + (size_t)(m0 + r) * lda + k0 + u, &As[(w * 2 + i) * 512]);
    }
    #pragma unroll
    for (int i = 0; i < 2; ++i) {
      const int o = (w * 2 + i) * 1024 + lane * 16;
      const int r = o >> 6;
      const int u = (((o >> 4) & 3) ^ ((r >> 1) & 3)) * 8;
      gload_lds16(Bp + (size_t)(n0 + r) * ldb + k0 + u, &Bs[(w * 2 + i) * 512]);
    }
    __syncthreads();

    bf8 af[4], bf_[4];
    #pragma unroll
    for (int i = 0; i < 4; ++i) {
      const int ar = wr + i * 16 + tl;
      const int br = wc + i * 16 + tl;
      af[i]  = *(const bf8*)&As[ar * 32 + ((g ^ ((ar >> 1) & 3)) * 8)];
      bf_[i] = *(const bf8*)&Bs[br * 32 + ((g ^ ((br >> 1) & 3)) * 8)];
    }
    #pragma unroll
    for (int mi = 0; mi < 4; ++mi)
      #pragma unroll
      for (int ni = 0; ni < 4; ++ni)
        acc[mi][ni] = __builtin_amdgcn_mfma_f32_16x16x32_bf16(af[mi], bf_[ni], acc[mi][ni], 0, 0, 0);
  }

  #pragma unroll
  for (int mi = 0; mi < 4; ++mi) {
    #pragma unroll
    for (int r = 0; r < 4; ++r) {
      const int row = m0 + wr + mi * 16 + g * 4 + r;
      #pragma unroll
      for (int ni = 0; ni < 4; ++ni) {
        const int col = n0 + wc + ni * 16 + tl;
        const float v = acc[mi][ni][r];
        if constexpr (OF32) ((float*)Cp)[(size_t)row * ldc + col] = v;
        else                ((uint16_t*)Cp)[(size_t)row * ldc + col] = f2bf(v);
      }
    }
  }
}

// ---------- GEMM KV (gemm2 structure, N=2048, split epilogue K|V) ----------
// B = [Wk;Wv] bf16 [2048, 8192]; blocks with n0 < 1024 write kbuf, else vbuf
// (block-uniform). Grid (16,32) = 512 blocks -> 2 blocks/CU, single launch.
__global__ __launch_bounds__(256)
void eagle3_gemmkv(const uint16_t* __restrict__ Ap, const uint16_t* __restrict__ Bp,
                   uint16_t* __restrict__ Kc, uint16_t* __restrict__ Vc)
{
  __shared__ __align__(16) uint16_t As[128 * 32];
  __shared__ __align__(16) uint16_t Bs[128 * 32];
  const int K = 8192, lda = 8192, ldb = 8192;

  const int nwg = gridDim.x * gridDim.y;
  const int bid = blockIdx.y * gridDim.x + blockIdx.x;
  const int qq = nwg >> 3;
  const int sw = (bid & 7) * qq + (bid >> 3);
  const int bx = sw % gridDim.x, by = sw / gridDim.x;
  const int m0 = by * 128, n0 = bx * 128;

  const int tid = threadIdx.x, lane = tid & 63, w = tid >> 6;
  const int tl = lane & 15, g = lane >> 4;
  const int wr = (w >> 1) * 64, wc = (w & 1) * 64;

  f4 acc[4][4] = {};

  for (int k0 = 0; k0 < K; k0 += 32) {
    __syncthreads();
    #pragma unroll
    for (int i = 0; i < 2; ++i) {
      const int o = (w * 2 + i) * 1024 + lane * 16;
      const int r = o >> 6;
      const int u = (((o >> 4) & 3) ^ ((r >> 1) & 3)) * 8;
      gload_lds16(Ap + (size_t)(m0 + r) * lda + k0 + u, &As[(w * 2 + i) * 512]);
    }
    #pragma unroll
    for (int i = 0; i < 2; ++i) {
      const int o = (w * 2 + i) * 1024 + lane * 16;
      const int r = o >> 6;
      const int u = (((o >> 4) & 3) ^ ((r >> 1) & 3)) * 8;
      gload_lds16(Bp + (size_t)(n0 + r) * ldb + k0 + u, &Bs[(w * 2 + i) * 512]);
    }
    __syncthreads();

    bf8 af[4], bf_[4];
    #pragma unroll
    for (int i = 0; i < 4; ++i) {
      const int ar = wr + i * 16 + tl;
      const int br = wc + i * 16 + tl;
      af[i]  = *(const bf8*)&As[ar * 32 + ((g ^ ((ar >> 1) & 3)) * 8)];
      bf_[i] = *(const bf8*)&Bs[br * 32 + ((g ^ ((br >> 1) & 3)) * 8)];
    }
    #pragma unroll
    for (int mi = 0; mi < 4; ++mi)
      #pragma unroll
      for (int ni = 0; ni < 4; ++ni)
        acc[mi][ni] = __builtin_amdgcn_mfma_f32_16x16x32_bf16(af[mi], bf_[ni], acc[mi][ni], 0, 0, 0);
  }

  uint16_t* dst = (n0 < 1024) ? Kc : Vc;     // block-uniform split
  const int c0 = n0 & 1023;
  #pragma unroll
  for (int mi = 0; mi < 4; ++mi) {
    #pragma unroll
    for (int r = 0; r < 4; ++r) {
      const int row = m0 + wr + mi * 16 + g * 4 + r;
      #pragma unroll
      for (int ni = 0; ni < 4; ++ni) {
        const int col = c0 + wc + ni * 16 + tl;
        dst[(size_t)row * 1024 + col] = f2bf(acc[mi][ni][r]);
      }
    }
  }
}

// ---------- GEMM v5 (256x256, BK=64, 8-phase m201-style schedule) ----------
template<bool OF32>
__global__ __launch_bounds__(512, 2)
void eagle3_gemm5(const uint16_t* __restrict__ Ap, const uint16_t* __restrict__ Bp,
                  void* __restrict__ Cp, int K, int lda, int ldb, int ldc)
{
  __shared__ __align__(16) uint16_t As[2][2][128 * 64];
  __shared__ __align__(16) uint16_t Bs[2][2][128 * 64];

  int bx, by;
  const int bid = blockIdx.y * gridDim.x + blockIdx.x;
  if (gridDim.x == 16 && gridDim.y == 16) {
    const int x = bid & 7, j = bid >> 3;
    by = (x >> 1) * 4 + (j >> 3);
    bx = (x & 1) * 8 + (j & 7);
  } else {
    const int nwg = gridDim.x * gridDim.y;
    const int qq = nwg >> 3;
    const int sw = (bid & 7) * qq + (bid >> 3);
    bx = sw % gridDim.x; by = sw / gridDim.x;
  }
  const int m0 = by * 256, n0 = bx * 256;

  const int tid = threadIdx.x, lane = tid & 63;
  const int tl = lane & 15, g = lane >> 4;
  const int w = tid >> 6;
  const int wm = w >> 2, wn = w & 3;
  const int bhf = wn >> 1;
  const int bl0 = (wn & 1) * 64;

  f4 acc[8][4] = {};
  const int NI = K >> 7;

  const int jr = tid >> 3;
  const int jc = ((tid & 7) ^ (jr & 7)) * 8;
  #define STG_A(slot, h, tt)                                                    \
    { const int kk_ = (tt) << 6;                                                \
      gload_lds16(Ap + (size_t)(m0 + (h)*128 + jr) * lda + kk_ + jc,            \
                  &As[slot][h][tid * 8]);                                       \
      gload_lds16(Ap + (size_t)(m0 + (h)*128 + 64 + jr) * lda + kk_ + jc,       \
                  &As[slot][h][(tid + 512) * 8]); }
  #define STG_B(slot, h, tt)                                                    \
    { const int kk_ = (tt) << 6;                                                \
      gload_lds16(Bp + (size_t)(n0 + (h)*128 + jr) * ldb + kk_ + jc,            \
                  &Bs[slot][h][tid * 8]);                                       \
      gload_lds16(Bp + (size_t)(n0 + (h)*128 + 64 + jr) * ldb + kk_ + jc,       \
                  &Bs[slot][h][(tid + 512) * 8]); }

  const int rk0 = ((0 + g) ^ (tl & 7)) * 8;
  const int rk1 = ((4 + g) ^ (tl & 7)) * 8;

  bf8 af[8], b0[4], b1[4];
  #define READ_A(slot, rh)                                                      \
    { _Pragma("unroll")                                                         \
      for (int m_ = 0; m_ < 4; ++m_) {                                          \
        const int R_ = (rh)*64 + m_*16 + tl;                                    \
        af[m_*2]   = *(const bf8*)&As[slot][wm][R_*64 + rk0];                   \
        af[m_*2+1] = *(const bf8*)&As[slot][wm][R_*64 + rk1];                   \
      } }
  #define READ_B(slot, ch, dst)                                                 \
    { _Pragma("unroll")                                                         \
      for (int c_ = 0; c_ < 2; ++c_) {                                          \
        const int R_ = bl0 + (ch)*32 + c_*16 + tl;                              \
        dst[c_*2]   = *(const bf8*)&Bs[slot][bhf][R_*64 + rk0];                 \
        dst[c_*2+1] = *(const bf8*)&Bs[slot][bhf][R_*64 + rk1];                 \
      } }
  #define MID_SYNC                                                              \
    __builtin_amdgcn_sched_barrier(0);                                          \
    __builtin_amdgcn_s_barrier();                                               \
    asm volatile("s_waitcnt lgkmcnt(0)" ::: "memory");                          \
    __builtin_amdgcn_sched_barrier(0);
  #define CLOSE_BAR                                                             \
    __builtin_amdgcn_sched_barrier(0);                                          \
    __builtin_amdgcn_s_barrier();                                               \
    __builtin_amdgcn_sched_barrier(0);
  #define MFMA16(rh, ch, bsrc)                                                  \
    { __builtin_amdgcn_s_setprio(1);                                            \
      _Pragma("unroll")                                                         \
      for (int m_ = 0; m_ < 4; ++m_) {                                          \
        _Pragma("unroll")                                                       \
        for (int c_ = 0; c_ < 2; ++c_) {                                        \
          acc[(rh)*4+m_][(ch)*2+c_] = __builtin_amdgcn_mfma_f32_16x16x32_bf16(  \
              af[m_*2],   bsrc[c_*2],   acc[(rh)*4+m_][(ch)*2+c_], 0, 0, 0);    \
          acc[(rh)*4+m_][(ch)*2+c_] = __builtin_amdgcn_mfma_f32_16x16x32_bf16(  \
              af[m_*2+1], bsrc[c_*2+1], acc[(rh)*4+m_][(ch)*2+c_], 0, 0, 0);    \
        } }                                                                     \
      __builtin_amdgcn_s_setprio(0); }

  STG_A(0, 0, 0); STG_A(0, 1, 0); STG_B(0, 0, 0); STG_B(0, 1, 0);
  STG_B(1, 0, 1); STG_B(1, 1, 1);
  asm volatile("s_waitcnt vmcnt(4)" ::: "memory");
  CLOSE_BAR;
  READ_B(0, 0, b0);

  for (int i = 0; i < NI; ++i) {
    const int T1 = 2 * i + 1;
    const bool more = (i + 1 < NI);

    READ_A(0, 0);
    STG_A(1, 0, T1);
    MID_SYNC; MFMA16(0, 0, b0); CLOSE_BAR;

    READ_B(0, 1, b1);
    STG_A(1, 1, T1);
    MID_SYNC; MFMA16(0, 1, b1); CLOSE_BAR;

    READ_A(0, 1);
    if (more) STG_B(0, 0, T1 + 1);
    MID_SYNC; MFMA16(1, 0, b0);
    if (more) { asm volatile("s_waitcnt vmcnt(6)" ::: "memory"); }
    else      { asm volatile("s_waitcnt vmcnt(4)" ::: "memory"); }
    CLOSE_BAR;

    READ_B(1, 0, b0);
    if (more) STG_B(0, 1, T1 + 1);
    MID_SYNC; MFMA16(1, 1, b1);
    if (more) { asm volatile("s_waitcnt vmcnt(4)" ::: "memory"); }
    else      { asm volatile("s_waitcnt vmcnt(0)" ::: "memory"); }
    CLOSE_BAR;

    READ_A(1, 0);
    if (more) STG_A(0, 0, T1 + 1);
    MID_SYNC; MFMA16(0, 0, b0); CLOSE_BAR;

    READ_B(1, 1, b1);
    if (more) STG_A(0, 1, T1 + 1);
    MID_SYNC; MFMA16(0, 1, b1); CLOSE_BAR;

    READ_A(1, 1);
    if (more) STG_B(1, 0, T1 + 2);
    MID_SYNC; MFMA16(1, 0, b0);
    if (more) { asm volatile("s_waitcnt vmcnt(6)" ::: "memory"); }
    CLOSE_BAR;

    if (more) { READ_B(0, 0, b0); STG_B(1, 1, T1 + 2); }
    MID_SYNC; MFMA16(1, 1, b1);
    if (more) { asm volatile("s_waitcnt vmcnt(4)" ::: "memory"); }
    CLOSE_BAR;
  }
  #undef STG_A
  #undef STG_B
  #undef READ_A
  #undef READ_B
  #undef MID_SYNC
  #undef CLOSE_BAR
  #undef MFMA16

  const int wr = wm * 128, wc = wn * 64;
  #pragma unroll
  for (int mi = 0; mi < 8; ++mi) {
    #pragma unroll
    for (int r = 0; r < 4; ++r) {
      const int row = m0 + wr + mi * 16 + g * 4 + r;
      #pragma unroll
      for (int ni = 0; ni < 4; ++ni) {
        const int col = n0 + wc + ni * 16 + tl;
        const float v = acc[mi][ni][r];
        if constexpr (OF32) ((float*)Cp)[(size_t)row * ldc + col] = v;
        else                ((uint16_t*)Cp)[(size_t)row * ldc + col] = f2bf(v);
      }
    }
  }
}

// ---------- RoPE (in-place on bf16, pairs (d, d+64)) — used for K only ----
__global__ __launch_bounds__(256)
void eagle3_rope(uint16_t* __restrict__ x, const float* __restrict__ cs,
                 const float* __restrict__ sn, int nh, int rowlen, int total)
{
  int id = blockIdx.x * 256 + threadIdx.x;
  if (id >= total) return;
  int d = id & 63;
  int t = id >> 6;
  int head = t & (nh - 1);
  int row = t / nh;
  int s = row & 2047;
  size_t base = (size_t)row * rowlen + head * 128;
  float c = cs[s * 128 + d], si = sn[s * 128 + d];
  float x1 = bf2f(x[base + d]), x2 = bf2f(x[base + d + 64]);
  x[base + d]      = f2bf(x1 * c - x2 * si);
  x[base + d + 64] = f2bf(x2 * c + x1 * si);
}

// ---------- V transpose: [b,t,h,d] -> [b,h,d,t] ----------
__global__ __launch_bounds__(256)
void eagle3_vtrans(const uint16_t* __restrict__ V, uint16_t* __restrict__ Vt)
{
  __shared__ uint16_t T[64 * 136];
  const int tid = threadIdx.x;
  const int t0 = blockIdx.x * 64;
  const int bh = blockIdx.y;
  const int b = bh >> 3, h = bh & 7;
  {
    const int r = tid >> 2, c0 = (tid & 3) * 32;
    const uint16_t* src = V + (size_t)(b * 2048 + t0 + r) * 1024 + h * 128 + c0;
    #pragma unroll
    for (int j = 0; j < 4; ++j)
      *(bf8*)&T[r * 136 + c0 + j * 8] = *(const bf8*)(src + j * 8);
  }
  __syncthreads();
  {
    const int d = tid >> 1, tc = (tid & 1) * 32;
    uint16_t* dst = Vt + ((size_t)bh * 128 + d) * 2048 + t0 + tc;
    #pragma unroll
    for (int cc = 0; cc < 4; ++cc) {
      bf8 v;
      #pragma unroll
      for (int j = 0; j < 8; ++j) v[j] = T[(tc + cc * 8 + j) * 136 + d];
      *(bf8*)&dst[cc * 8] = v;
    }
  }
}

// ---------- causal GQA flash attention v7 (unchanged) ----------
__global__ __launch_bounds__(512, 4)
void eagle3_flash7(const uint16_t* __restrict__ Q, const uint16_t* __restrict__ Kt,
                   const uint16_t* __restrict__ Vt, uint16_t* __restrict__ O,
                   const float* __restrict__ Cst, const float* __restrict__ Snt)
{
  __shared__ __align__(16) uint16_t Ks[2][64 * 128];   // 32 KB
  __shared__ __align__(16) uint16_t Vs[2][128 * 64];   // 32 KB
  __shared__ __align__(16) uint16_t Pl[8][16 * 64];    // 16 KB (per-wave, swz)

  const int tid = threadIdx.x, lane = tid & 63, w = tid >> 6;
  const int tl = lane & 15, g = lane >> 4;

  const int bid = (int)blockIdx.x + ((int)blockIdx.y << 4) + ((int)blockIdx.z << 9);
  const int xcd = bid & 7, idx = bid >> 3;
  const int grp = xcd * 2 + (idx >> 6);
  const int j   = idx & 63;
  const int b = grp >> 3, hkv = grp & 7;
  const int hq = hkv * 4 + (j & 3);
  const int qt = 15 - (j >> 2);
  const int qrow0 = qt * 128 + w * 16;
  const int ntb = 2 * qt + 2;

  bf8 qf[4];
  {
    const int srow = qrow0 + tl;
    const uint16_t* qp = Q + ((size_t)(b * 2048 + srow)) * 4096 + hq * 128 + g * 8;
    #pragma unroll
    for (int kb = 0; kb < 4; ++kb) qf[kb] = *(const bf8*)(qp + kb * 32);
    const float* cp = Cst + (size_t)srow * 128 + g * 8;
    const float* sp = Snt + (size_t)srow * 128 + g * 8;
    #pragma unroll
    for (int kb = 0; kb < 2; ++kb) {
      const float4 c0 = *(const float4*)(cp + kb * 32);
      const float4 c1 = *(const float4*)(cp + kb * 32 + 4);
      const float4 s0 = *(const float4*)(sp + kb * 32);
      const float4 s1 = *(const float4*)(sp + kb * 32 + 4);
      const float cc[8] = {c0.x,c0.y,c0.z,c0.w,c1.x,c1.y,c1.z,c1.w};
      const float ss[8] = {s0.x,s0.y,s0.z,s0.w,s1.x,s1.y,s1.z,s1.w};
      #pragma unroll
      for (int e = 0; e < 8; ++e) {
        const float x1 = bf2f((uint16_t)qf[kb][e]);
        const float x2 = bf2f((uint16_t)qf[kb + 2][e]);
        qf[kb][e]     = (short)f2bf(x1 * cc[e] - x2 * ss[e]);
        qf[kb + 2][e] = (short)f2bf(x2 * cc[e] + x1 * ss[e]);
      }
    }
  }

  const uint16_t* Kbase = Kt + (size_t)b * 2048 * 1024 + hkv * 128;
  const uint16_t* Vtb   = Vt + ((size_t)(b * 8 + hkv) * 128) * 2048;

  bf8 onesf = {};
  if (tl == 0) {
    #pragma unroll
    for (int q8 = 0; q8 < 8; ++q8) onesf[q8] = (short)0x3F80;
  }

  f4 acc[8] = {};
  f4 accl = {};
  float rm[4] = {-3e38f, -3e38f, -3e38f, -3e38f};
  const float KS = 0.1275174f;                // log2(e)/sqrt(128)

  #define STAGE_TILE(buf, t0s)                                                   \
    {                                                                            \
      _Pragma("unroll")                                                          \
      for (int i = 0; i < 2; ++i) {                                              \
        const int f = i * 512 + tid;                                             \
        const int r = f >> 4, c = f & 15;                                        \
        gload_lds16(Kbase + (size_t)((t0s) + r) * 1024 + ((c ^ (r & 7)) * 8),    \
                    &Ks[buf][(i * 512 + w * 64) * 8]);                           \
      }                                                                          \
      _Pragma("unroll")                                                          \
      for (int i = 0; i < 2; ++i) {                                              \
        const int f = i * 512 + tid;                                             \
        const int d = f >> 3, c = f & 7;                                         \
        gload_lds16(Vtb + (size_t)d * 2048 + (t0s) + ((c ^ (d & 7)) * 8),        \
                    &Vs[buf][(i * 512 + w * 64) * 8]);                           \
      }                                                                          \
    }

  STAGE_TILE(0, 0);

  for (int tb = 0; tb < ntb; ++tb) {
    const int cur = tb & 1;
    const int t0 = tb * 64;

    if (tb + 1 < ntb) {
      STAGE_TILE(cur ^ 1, t0 + 64);
      asm volatile("s_waitcnt vmcnt(4)" ::: "memory");
    } else {
      asm volatile("s_waitcnt vmcnt(0)" ::: "memory");
    }
    __builtin_amdgcn_sched_barrier(0);
    __builtin_amdgcn_s_barrier();

    const bool active = (t0 <= qrow0 + 15);
    if (active) {
      f4 s[4] = {};
      __builtin_amdgcn_s_setprio(1);
      #pragma unroll
      for (int cf = 0; cf < 4; ++cf) {
        #pragma unroll
        for (int kb = 0; kb < 4; ++kb) {
          const bf8 kf = *(const bf8*)&Ks[cur][(cf * 16 + tl) * 128 +
                                              (((kb * 4 + g) ^ (tl & 7)) * 8)];
          s[cf] = __builtin_amdgcn_mfma_f32_16x16x32_bf16(qf[kb], kf, s[cf], 0, 0, 0);
        }
      }
      __builtin_amdgcn_s_setprio(0);

      const bool edge = (t0 + 63 > qrow0);
      float p[4][4];
      #pragma unroll
      for (int r = 0; r < 4; ++r) {
        float v[4];
        #pragma unroll
        for (int cf = 0; cf < 4; ++cf) v[cf] = s[cf][r];
        if (edge) {
          const int qg = qrow0 + g * 4 + r;
          #pragma unroll
          for (int cf = 0; cf < 4; ++cf)
            if (t0 + cf * 16 + tl > qg) v[cf] = -3e38f;
        }
        float mx = fmaxf(fmaxf(v[0], v[1]), fmaxf(v[2], v[3]));
        mx = fmaxf(mx, __shfl_xor(mx, 1));
        mx = fmaxf(mx, __shfl_xor(mx, 2));
        mx = fmaxf(mx, __shfl_xor(mx, 4));
        mx = fmaxf(mx, __shfl_xor(mx, 8));
        if (mx > rm[r]) {
          const float corr = exp2f((rm[r] - mx) * KS);
          #pragma unroll
          for (int df = 0; df < 8; ++df) acc[df][r] *= corr;
          accl[r] *= corr;
          rm[r] = mx;
        }
        #pragma unroll
        for (int cf = 0; cf < 4; ++cf) p[r][cf] = exp2f((v[cf] - rm[r]) * KS);
      }

      #pragma unroll
      for (int r = 0; r < 4; ++r) {
        const uint32_t pk0 = cvtpk(p[r][0], p[r][1]);
        const uint32_t pk1 = cvtpk(p[r][2], p[r][3]);
        const int row = g * 4 + r;
        const int sw = row & 7;
        uint16_t* Pw = &Pl[w][row * 64 + (tl & 7)];
        Pw[(((tl >> 3) + 0) ^ sw) * 8] = (uint16_t)pk0;
        Pw[(((tl >> 3) + 2) ^ sw) * 8] = (uint16_t)(pk0 >> 16);
        Pw[(((tl >> 3) + 4) ^ sw) * 8] = (uint16_t)pk1;
        Pw[(((tl >> 3) + 6) ^ sw) * 8] = (uint16_t)(pk1 >> 16);
      }
      const bf8 pf0 = *(const bf8*)&Pl[w][tl * 64 + ((g ^ (tl & 7)) * 8)];
      const bf8 pf1 = *(const bf8*)&Pl[w][tl * 64 + (((4 + g) ^ (tl & 7)) * 8)];

      __builtin_amdgcn_s_setprio(1);
      accl = __builtin_amdgcn_mfma_f32_16x16x32_bf16(pf0, onesf, accl, 0, 0, 0);
      accl = __builtin_amdgcn_mfma_f32_16x16x32_bf16(pf1, onesf, accl, 0, 0, 0);
      #pragma unroll
      for (int df = 0; df < 8; ++df) {
        const int vrow = (df * 16 + tl) * 64;
        const bf8 v0 = *(const bf8*)&Vs[cur][vrow + ((g ^ (tl & 7)) * 8)];
        const bf8 v1 = *(const bf8*)&Vs[cur][vrow + (((4 + g) ^ (tl & 7)) * 8)];
        acc[df] = __builtin_amdgcn_mfma_f32_16x16x32_bf16(pf0, v0, acc[df], 0, 0, 0);
        acc[df] = __builtin_amdgcn_mfma_f32_16x16x32_bf16(pf1, v1, acc[df], 0, 0, 0);
      }
      __builtin_amdgcn_s_setprio(0);
    }

    __builtin_amdgcn_s_barrier();
  }
  #undef STAGE_TILE

  #pragma unroll
  for (int r = 0; r < 4; ++r) {
    const float l = __shfl(accl[r], lane & 48);
    const float inv = 1.0f / l;
    const size_t ob = ((size_t)(b * 2048 + qrow0 + g * 4 + r)) * 4096 + hq * 128 + tl;
    #pragma unroll
    for (int df = 0; df < 8; ++df)
      O[ob + df * 16] = f2bf(acc[df][r] * inv);
  }
}

// ---------- launch ----------
extern "C" void kernel_launch(void* const* d_in, const int* in_sizes, int n_in,
                              void* d_out, int out_size, void* d_ws, size_t ws_size,
                              hipStream_t stream) {
  const float* hs   = (const float*)d_in[0];
  const float* cosT = (const float*)d_in[2];
  const float* sinT = (const float*)d_in[3];
  const float* Wq   = (const float*)d_in[4];
  const float* Wk   = (const float*)d_in[5];
  const float* Wv   = (const float*)d_in[6];
  const float* Wo   = (const float*)d_in[7];

  // ---- workspace liveness ----
  // hsb = d_out [4096,8192] bf16 (64MB)       live: cvt -> KV gemm
  // [ 0M,32M) qb     live: Q gemm -> flash; then wobf
  // [32M,40M) kbuf   live: KV gemm -> flash
  // [40M,48M) vbuf   live: KV gemm -> vtrans
  // [48M,..)  weights (serial): Wq 64MB (fullq, ws>=112MiB), then [Wk;Wv]
  //           32MB at [48M,80M)
  // [72M,80M) vt     live: vtrans -> flash (over dead wkv tail)
  // [40M,72M) ctx    live: flash -> Wo gemm (over dead bufs)
  char* ws = (char*)d_ws;
  uint16_t* qb    = (uint16_t*)(ws);
  uint16_t* kbuf  = (uint16_t*)(ws + 33554432);
  uint16_t* vbuf  = (uint16_t*)(ws + 41943040);
  uint16_t* whalf = (uint16_t*)(ws + 50331648);
  uint16_t* vt    = (uint16_t*)(ws + 75497472);
  uint16_t* ctx   = (uint16_t*)(ws + 41943040);
  uint16_t* hsb   = (uint16_t*)d_out;
  uint16_t* wobf  = qb;

  const dim3 blk(256);
  const bool fullq = (ws_size >= (size_t)117440512);   // 112 MiB

  // 1) hs f32 -> bf16 (once)
  eagle3_cvt<<<dim3(2048), blk, 0, stream>>>(hs, hsb, 4194304);

  // 2) Q projection
  if (fullq) {
    eagle3_cvt<<<dim3(2048), blk, 0, stream>>>(Wq, whalf, 4194304);
    eagle3_gemm5<false><<<dim3(16, 16), dim3(512), 0, stream>>>(
        hsb, whalf, (void*)qb, 8192, 8192, 8192, 4096);
  } else {
    eagle3_cvt<<<dim3(2048), blk, 0, stream>>>(Wq, whalf, 2097152);
    eagle3_gemm2<false><<<dim3(16, 32), blk, 0, stream>>>(
        hsb, whalf, (void*)qb, 8192, 8192, 8192, 4096);
    eagle3_cvt<<<dim3(2048), blk, 0, stream>>>(Wq + 16777216, whalf, 2097152);
    eagle3_gemm2<false><<<dim3(16, 32), blk, 0, stream>>>(
        hsb, whalf, (void*)(qb + 2048), 8192, 8192, 8192, 4096);
  }

  // 3) K and V projections fused: B = [Wk;Wv] (one cvt launch, one gemm)
  eagle3_cvt2<<<dim3(2048), blk, 0, stream>>>(
      Wk, whalf, 1048576, Wv, whalf + 8388608, 1048576);
  eagle3_gemmkv<<<dim3(16, 32), blk, 0, stream>>>(hsb, whalf, kbuf, vbuf);

  // 4) RoPE on K only (Q rope fused into flash7) + V transpose
  eagle3_rope<<<dim3(8192), blk, 0, stream>>>(kbuf, cosT, sinT, 8, 1024, 2097152);
  eagle3_vtrans<<<dim3(32, 16), blk, 0, stream>>>(vbuf, vt);

  // 5) causal GQA flash attention (with in-register Q RoPE) -> ctx
  eagle3_flash7<<<dim3(16, 32, 2), dim3(512), 0, stream>>>(
      qb, kbuf, vt, ctx, cosT, sinT);

  // 6) output projection: out = ctx * Wo^T (f32 out over dead hsb)
  eagle3_cvt<<<dim3(2048), blk, 0, stream>>>(Wo, wobf, 2097152);
  eagle3_gemm5<true><<<dim3(16, 16), dim3(512), 0, stream>>>(
      ctx, wobf, d_out, 4096, 4096, 4096, 4096);
}